// Round 1
// baseline (700.807 us; speedup 1.0000x reference)
//
#include <hip/hip_runtime.h>
#include <math.h>

// ---------------------------------------------------------------------------
// ASAP pooling block, fixed shapes.
// ---------------------------------------------------------------------------
constexpr int N_ = 20000;
constexpr int E_ = 320000;
constexpr int M_ = E_ + N_;      // edges incl. self loops
constexpr int F_ = 64;
constexpr int K_ = 256;
constexpr int TCAP = 32768;      // S-triplet capacity (expected ~4400)
constexpr int OUT_WORDS = K_ * F_ + K_ * K_ + K_;   // 82176

// ---- workspace layout (word offsets) --------------------------------------
constexpr size_t O_RR   = 0;
constexpr size_t O_CC   = O_RR + M_;
constexpr size_t O_EID  = O_CC + M_;
constexpr size_t O_NORM = O_EID + M_;
constexpr size_t O_SCORE= O_NORM + M_;                 // reused as normalized sc
constexpr size_t O_BUFA = O_SCORE + M_;
constexpr size_t O_BUFB = O_BUFA + (size_t)N_ * F_;
constexpr size_t O_BUFC = O_BUFB + (size_t)N_ * F_;
constexpr size_t O_CPTR = O_BUFC + (size_t)N_ * F_;    // N+1
constexpr size_t O_Q1   = O_CPTR + N_ + 1;
constexpr size_t O_Q2   = O_Q1 + N_;
constexpr size_t O_SMAX = O_Q2 + N_;
constexpr size_t O_DEN  = O_SMAX + N_;
constexpr size_t O_A    = O_DEN + N_;
constexpr size_t O_B    = O_A + N_;
constexpr size_t O_C3   = O_B + N_;
constexpr size_t O_FIT  = O_C3 + N_;
constexpr size_t O_CANDA= O_FIT + N_;
constexpr size_t O_CANDB= O_CANDA + N_;
constexpr size_t O_INV  = O_CANDB + N_;
constexpr size_t O_TPTR = O_INV + N_;                  // N+1
constexpr size_t O_TI   = O_TPTR + N_ + 1;
constexpr size_t O_TK   = O_TI + TCAP;
constexpr size_t O_TV   = O_TK + TCAP;
constexpr size_t O_TIDX = O_TV + TCAP;
constexpr size_t O_SEL  = O_TIDX + TCAP;               // 256
constexpr size_t O_PERM = O_SEL + K_;                  // 256 (int)
constexpr size_t O_FITS = O_PERM + K_;                 // 256 (f32)
// zero-initialized region:
constexpr size_t O_ZR   = O_FITS + K_;
constexpr size_t O_CNT  = O_ZR;                        // N
constexpr size_t O_CUR  = O_CNT + N_;                  // N
constexpr size_t O_TCNT = O_CUR + N_;                  // N
constexpr size_t O_TCUR = O_TCNT + N_;                 // N
constexpr size_t O_HIST = O_TCUR + N_;                 // 65536
constexpr size_t O_CTRL = O_HIST + 65536;              // 8: rem,d,cntA,cntB,sel,trip
constexpr size_t ZR_WORDS = O_CTRL + 8 - O_ZR;

// ---------------------------------------------------------------------------
__global__ void init_k(unsigned* __restrict__ zr, float* __restrict__ dout) {
  int g = blockIdx.x * blockDim.x + threadIdx.x;
  if (g < (int)ZR_WORDS) zr[g] = (g == (int)(O_CTRL - O_ZR)) ? 256u : 0u; // ctrl[0]=K
  if (g < OUT_WORDS) dout[g] = 0.0f;
}

__global__ void build_edges_k(const int* __restrict__ ei, int* __restrict__ rr,
                              int* __restrict__ cc, unsigned* __restrict__ cnt) {
  int g = blockIdx.x * blockDim.x + threadIdx.x;
  if (g >= M_) return;
  int r, c;
  if (g < E_) { r = ei[g]; c = ei[E_ + g]; } else { r = g - E_; c = r; }
  rr[g] = r; cc[g] = c;
  atomicAdd(&cnt[c], 1u);
}

// single-block exclusive prefix (n bins -> ptr[n+1])
__global__ void prefix_k(const unsigned* __restrict__ cnt, unsigned* __restrict__ ptr, int n) {
  __shared__ unsigned part[1024];
  int t = threadIdx.x;
  int chunk = (n + 1023) >> 10;
  int i0 = t * chunk;
  unsigned s = 0;
  for (int j = 0; j < chunk; ++j) { int i = i0 + j; if (i < n) s += cnt[i]; }
  part[t] = s; __syncthreads();
  for (int off = 1; off < 1024; off <<= 1) {
    unsigned v = (t >= off) ? part[t - off] : 0u;
    __syncthreads();
    part[t] += v;
    __syncthreads();
  }
  unsigned run = part[t] - s;
  for (int j = 0; j < chunk; ++j) {
    int i = i0 + j;
    if (i < n) { ptr[i] = run; run += cnt[i]; }
  }
  if (t == 0) ptr[n] = part[1023];
}

__global__ void scatter_eid_k(const int* __restrict__ cc, const unsigned* __restrict__ cptr,
                              unsigned* __restrict__ cur, unsigned* __restrict__ eid) {
  int g = blockIdx.x * blockDim.x + threadIdx.x;
  if (g >= M_) return;
  int c = cc[g];
  unsigned pos = cptr[c] + atomicAdd(&cur[c], 1u);
  eid[pos] = (unsigned)g;
}

__global__ void norm_k(const int* __restrict__ rr, const int* __restrict__ cc,
                       const unsigned* __restrict__ cptr, float* __restrict__ nrm) {
  int g = blockIdx.x * blockDim.x + threadIdx.x;
  if (g >= M_) return;
  int r = rr[g], c = cc[g];
  float dr = (float)(cptr[r + 1] - cptr[r]);
  float dc = (float)(cptr[c + 1] - cptr[c]);
  nrm[g] = (1.0f / sqrtf(dr)) * (1.0f / sqrtf(dc));
}

// Y[n,64] = X[n,64] @ W[64,64] (+bias). Tiled: 64 rows/block, 256 threads.
template<bool BIAS>
__global__ void gemm64_k(const float* __restrict__ X, const float* __restrict__ W,
                         const float* __restrict__ bias, float* __restrict__ Y) {
  __shared__ float xs[64][64];
  __shared__ float wsh[64][64];
  int t = threadIdx.x;
  int r0 = blockIdx.x * 64;
  for (int i = 0; i < 16; ++i) {
    int idx = t + i * 256;
    wsh[idx >> 6][idx & 63] = W[idx];
  }
  for (int i = 0; i < 16; ++i) {
    int idx = t + i * 256;
    int r = idx >> 6, c = idx & 63;
    xs[r][c] = (r0 + r < N_) ? X[(size_t)(r0 + r) * F_ + c] : 0.0f;
  }
  __syncthreads();
  int c = t & 63, rg = t >> 6;
  float acc[16];
#pragma unroll
  for (int m = 0; m < 16; ++m) acc[m] = 0.0f;
  for (int k = 0; k < 64; ++k) {
    float w = wsh[k][c];
#pragma unroll
    for (int m = 0; m < 16; ++m) acc[m] += xs[rg + 4 * m][k] * w;
  }
  float bv = BIAS ? bias[c] : 0.0f;
  for (int m = 0; m < 16; ++m) {
    int r = r0 + rg + 4 * m;
    if (r < N_) Y[(size_t)r * F_ + c] = acc[m] + bv;
  }
}

// MODE 0: weighted sum + bias + relu (GCN). MODE 1: max. MODE 2: weighted sum.
// one wave per node, lane = feature.
template<int MODE>
__global__ void agg_k(const float* __restrict__ H, const int* __restrict__ rr,
                      const float* __restrict__ wvec, const unsigned* __restrict__ cptr,
                      const unsigned* __restrict__ eid, const float* __restrict__ bias,
                      float* __restrict__ Y) {
  int wid = blockIdx.x * (blockDim.x >> 6) + (threadIdx.x >> 6);
  int lane = threadIdx.x & 63;
  if (wid >= N_) return;
  unsigned p0 = cptr[wid], p1 = cptr[wid + 1];
  float acc = (MODE == 1) ? -INFINITY : 0.0f;
  for (unsigned p = p0; p < p1; ++p) {
    unsigned e = eid[p];
    int s = rr[e];
    float h = H[(size_t)s * F_ + lane];
    if (MODE == 1) acc = fmaxf(acc, h);
    else           acc += wvec[e] * h;
  }
  if (MODE == 0) acc = fmaxf(acc + bias[lane], 0.0f);
  Y[(size_t)wid * F_ + lane] = acc;
}

// q1[i] = xq_lin[i,:]·attW[0:64], q2[i] = x2[i,:]·attW[64:128]
__global__ void dots_k(const float* __restrict__ XQ, const float* __restrict__ X2,
                       const float* __restrict__ attW, float* __restrict__ q1,
                       float* __restrict__ q2) {
  int wid = blockIdx.x * (blockDim.x >> 6) + (threadIdx.x >> 6);
  int lane = threadIdx.x & 63;
  if (wid >= N_) return;
  float p1 = XQ[(size_t)wid * F_ + lane] * attW[lane];
  float p2 = X2[(size_t)wid * F_ + lane] * attW[64 + lane];
  for (int off = 32; off; off >>= 1) {
    p1 += __shfl_down(p1, off);
    p2 += __shfl_down(p2, off);
  }
  if (lane == 0) { q1[wid] = p1; q2[wid] = p2; }
}

__global__ void score_k(const int* __restrict__ rr, const int* __restrict__ cc,
                        const float* __restrict__ q1, const float* __restrict__ q2,
                        const float* __restrict__ attb, float* __restrict__ score) {
  int g = blockIdx.x * blockDim.x + threadIdx.x;
  if (g >= M_) return;
  float s = q1[cc[g]] + q2[rr[g]] + attb[0];
  score[g] = (s > 0.0f) ? s : 0.2f * s;   // leaky_relu 0.2
}

__global__ void smaxden_k(const float* __restrict__ score, const unsigned* __restrict__ cptr,
                          const unsigned* __restrict__ eid, float* __restrict__ smax,
                          float* __restrict__ den) {
  int i = blockIdx.x * blockDim.x + threadIdx.x;
  if (i >= N_) return;
  unsigned p0 = cptr[i], p1 = cptr[i + 1];
  float m = -INFINITY;
  for (unsigned p = p0; p < p1; ++p) m = fmaxf(m, score[eid[p]]);
  float d = 0.0f;
  for (unsigned p = p0; p < p1; ++p) d += expf(score[eid[p]] - m);
  smax[i] = m; den[i] = d;
}

__global__ void scnorm_k(const int* __restrict__ cc, const float* __restrict__ smax,
                         const float* __restrict__ den, float* __restrict__ score) {
  int g = blockIdx.x * blockDim.x + threadIdx.x;
  if (g >= M_) return;
  int c = cc[g];
  score[g] = expf(score[g] - smax[c]) / den[c];
}

// a = xc·le1W + le1b ; b = xc·le2W ; c3 = xc·le3W + le3b
__global__ void fitpre_k(const float* __restrict__ XC, const float* __restrict__ le1W,
                         const float* __restrict__ le1b, const float* __restrict__ le2W,
                         const float* __restrict__ le3W, const float* __restrict__ le3b,
                         float* __restrict__ av, float* __restrict__ bv, float* __restrict__ c3) {
  int wid = blockIdx.x * (blockDim.x >> 6) + (threadIdx.x >> 6);
  int lane = threadIdx.x & 63;
  if (wid >= N_) return;
  float x = XC[(size_t)wid * F_ + lane];
  float s1 = x * le1W[lane], s2 = x * le2W[lane], s3 = x * le3W[lane];
  for (int off = 32; off; off >>= 1) {
    s1 += __shfl_down(s1, off);
    s2 += __shfl_down(s2, off);
    s3 += __shfl_down(s3, off);
  }
  if (lane == 0) { av[wid] = s1 + le1b[0]; bv[wid] = s2; c3[wid] = s3 + le3b[0]; }
}

__global__ void fitness_k(const unsigned* __restrict__ cptr, const unsigned* __restrict__ eid,
                          const int* __restrict__ rr, const float* __restrict__ av,
                          const float* __restrict__ bv, const float* __restrict__ c3,
                          float* __restrict__ fit) {
  int i = blockIdx.x * blockDim.x + threadIdx.x;
  if (i >= N_) return;
  unsigned p0 = cptr[i], p1 = cptr[i + 1];
  float s = 0.0f;
  for (unsigned p = p0; p < p1; ++p) s += av[rr[eid[p]]];
  float deg = (float)(p1 - p0);
  float val = s - deg * bv[i] + c3[i];
  fit[i] = 1.0f / (1.0f + expf(-val));
}

// ---- exact top-K radix select: digits (fbits>>16, fbits&0xFFFF, 0xFFFF-idx) ----
template<int LVL>
__device__ __forceinline__ unsigned digit_of(unsigned i, const float* fit) {
  unsigned fb = __float_as_uint(fit[i]);
  if (LVL == 0) return fb >> 16;
  if (LVL == 1) return fb & 0xFFFFu;
  return 0xFFFFu - i;
}

template<int LVL>
__global__ void radix_hist_k(const float* __restrict__ fit, const unsigned* __restrict__ src,
                             const unsigned* __restrict__ cntp, unsigned* __restrict__ hist) {
  int g = blockIdx.x * blockDim.x + threadIdx.x;
  int cnt = (LVL == 0) ? N_ : (int)*cntp;
  if (g >= cnt) return;
  unsigned i = (LVL == 0) ? (unsigned)g : src[g];
  atomicAdd(&hist[digit_of<LVL>(i, fit)], 1u);
}

// find digit d: suffix(d+1) < rem <= suffix(d); update rem; zero hist.
__global__ void radix_scan_k(unsigned* __restrict__ hist, unsigned* __restrict__ ctrl) {
  __shared__ unsigned part[1024];
  int t = threadIdx.x;
  int base = t * 64;
  unsigned s = 0;
  for (int j = 0; j < 64; ++j) s += hist[base + j];
  part[t] = s; __syncthreads();
  for (int off = 1; off < 1024; off <<= 1) {
    unsigned v = (t + off < 1024) ? part[t + off] : 0u;
    __syncthreads();
    part[t] += v;
    __syncthreads();
  }
  unsigned rem = ctrl[0];
  __syncthreads();   // everyone holds rem before the winner overwrites ctrl[0]
  unsigned sufNext = (t < 1023) ? part[t + 1] : 0u;
  if (part[t] >= rem && sufNext < rem) {
    unsigned running = sufNext;
    for (int b = 63; b >= 0; --b) {
      unsigned h = hist[base + b];
      running += h;
      if (running >= rem) {
        ctrl[1] = (unsigned)(base + b);
        ctrl[0] = rem - (running - h);
        break;
      }
    }
  }
  __syncthreads();
  for (int j = 0; j < 64; ++j) hist[base + j] = 0u;
}

template<int LVL>
__global__ void radix_emit_k(const float* __restrict__ fit, const unsigned* __restrict__ src,
                             const unsigned* __restrict__ cntp, unsigned* __restrict__ ctrl,
                             unsigned* __restrict__ sel, unsigned* __restrict__ dst,
                             unsigned* __restrict__ dstcnt) {
  int g = blockIdx.x * blockDim.x + threadIdx.x;
  int cnt = (LVL == 0) ? N_ : (int)*cntp;
  if (g >= cnt) return;
  unsigned i = (LVL == 0) ? (unsigned)g : src[g];
  unsigned dg = digit_of<LVL>(i, fit);
  unsigned d = ctrl[1];
  if (dg > d) {
    sel[atomicAdd(&ctrl[4], 1u)] = i;
  } else if (dg == d) {
    if (LVL == 2) sel[atomicAdd(&ctrl[4], 1u)] = i;
    else          dst[atomicAdd(dstcnt, 1u)] = i;
  }
}

__global__ void fill_inv_k(int* __restrict__ inv) {
  int g = blockIdx.x * blockDim.x + threadIdx.x;
  if (g < N_) inv[g] = K_;
}

// bitonic sort of 256 selected by (fitness desc, idx asc); emit perm & inv
__global__ void sort_sel_k(const unsigned* __restrict__ sel, const float* __restrict__ fit,
                           unsigned* __restrict__ perm_i, float* __restrict__ fit_s,
                           float* __restrict__ out_perm, int* __restrict__ inv) {
  __shared__ unsigned long long keys[K_];
  int t = threadIdx.x;
  unsigned i = sel[t];
  unsigned fb = __float_as_uint(fit[i]);
  keys[t] = ((unsigned long long)fb << 32) | (unsigned long long)(0xFFFFFFFFu - i);
  __syncthreads();
  for (unsigned k = 2; k <= K_; k <<= 1) {
    for (unsigned j = k >> 1; j > 0; j >>= 1) {
      unsigned partner = t ^ j;
      unsigned long long a = keys[t], b = keys[partner];
      bool desc = ((t & k) == 0);
      bool tFirst = ((unsigned)t < partner);
      unsigned long long mx = (a > b) ? a : b;
      unsigned long long mn = (a > b) ? b : a;
      unsigned long long nv = (desc == tFirst) ? mx : mn;
      __syncthreads();
      keys[t] = nv;
      __syncthreads();
    }
  }
  unsigned long long kk = keys[t];
  unsigned idx = 0xFFFFFFFFu - (unsigned)(kk & 0xFFFFFFFFu);
  perm_i[t] = idx;
  fit_s[t] = __uint_as_float((unsigned)(kk >> 32));
  out_perm[t] = (float)idx;
  inv[idx] = t;
}

__global__ void xnew_k(const float* __restrict__ XC, const unsigned* __restrict__ perm_i,
                       const float* __restrict__ fit_s, float* __restrict__ out) {
  int g = blockIdx.x * blockDim.x + threadIdx.x;
  if (g >= K_ * F_) return;
  int k = g >> 6, f = g & 63;
  out[g] = XC[(size_t)perm_i[k] * F_ + f] * fit_s[k];
}

__global__ void trip_build_k(const int* __restrict__ rr, const int* __restrict__ cc,
                             const int* __restrict__ inv, const float* __restrict__ sc,
                             int* __restrict__ ti, int* __restrict__ tk, float* __restrict__ tv,
                             unsigned* __restrict__ tcnt, unsigned* __restrict__ ctrl) {
  int g = blockIdx.x * blockDim.x + threadIdx.x;
  if (g >= M_) return;
  int k = inv[cc[g]];
  if (k >= K_) return;
  unsigned j = atomicAdd(&ctrl[5], 1u);
  if (j < (unsigned)TCAP) {
    int r = rr[g];
    ti[j] = r; tk[j] = k; tv[j] = sc[g];
    atomicAdd(&tcnt[r], 1u);
  }
}

__global__ void trip_scatter_k(const int* __restrict__ ti, const unsigned* __restrict__ tptr,
                               unsigned* __restrict__ tcur, unsigned* __restrict__ tidx,
                               const unsigned* __restrict__ ctrl) {
  int g = blockIdx.x * blockDim.x + threadIdx.x;
  unsigned cnt = ctrl[5]; if (cnt > (unsigned)TCAP) cnt = TCAP;
  if (g >= (int)cnt) return;
  int i = ti[g];
  unsigned pos = tptr[i] + atomicAdd(&tcur[i], 1u);
  tidx[pos] = (unsigned)g;
}

// A[k1,k2] += sum over edges of S[row,k1]*S[col,k2]  (triplet pair expansion)
__global__ void anew_k(const int* __restrict__ rr, const int* __restrict__ cc,
                       const unsigned* __restrict__ tptr, const unsigned* __restrict__ tidx,
                       const int* __restrict__ tk, const float* __restrict__ tv,
                       float* __restrict__ A) {
  int g = blockIdx.x * blockDim.x + threadIdx.x;
  if (g >= M_) return;
  int i = rr[g], j = cc[g];
  unsigned a0 = tptr[i], a1 = tptr[i + 1];
  if (a0 == a1) return;
  unsigned b0 = tptr[j], b1 = tptr[j + 1];
  if (b0 == b1) return;
  for (unsigned pa = a0; pa < a1; ++pa) {
    unsigned ta = tidx[pa];
    int k1 = tk[ta];
    float va = tv[ta];
    float* Arow = A + (size_t)k1 * K_;
    for (unsigned pb = b0; pb < b1; ++pb) {
      unsigned tb = tidx[pb];
      atomicAdd(&Arow[tk[tb]], va * tv[tb]);
    }
  }
}

__global__ void adiag_k(float* __restrict__ A) {
  int t = threadIdx.x;
  if (t < K_) A[(size_t)t * K_ + t] = 1.0f;
}

// ---------------------------------------------------------------------------
extern "C" void kernel_launch(void* const* d_in, const int* in_sizes, int n_in,
                              void* d_out, int out_size, void* d_ws, size_t ws_size,
                              hipStream_t stream) {
  const float* x     = (const float*)d_in[0];
  const int*   ei    = (const int*)d_in[1];
  const float* W0    = (const float*)d_in[2];
  const float* b0    = (const float*)d_in[3];
  const float* W1    = (const float*)d_in[4];
  const float* b1    = (const float*)d_in[5];
  const float* linW  = (const float*)d_in[6];
  const float* linb  = (const float*)d_in[7];
  const float* attW  = (const float*)d_in[8];
  const float* attb  = (const float*)d_in[9];
  const float* le1W  = (const float*)d_in[10];
  const float* le1b  = (const float*)d_in[11];
  const float* le2W  = (const float*)d_in[12];
  const float* le3W  = (const float*)d_in[13];
  const float* le3b  = (const float*)d_in[14];

  float*    wf = (float*)d_ws;
  unsigned* wu = (unsigned*)d_ws;
  int*      wi = (int*)d_ws;
  float*    out = (float*)d_out;

  int*      rr    = wi + O_RR;
  int*      cc    = wi + O_CC;
  unsigned* eid   = wu + O_EID;
  float*    nrm   = wf + O_NORM;
  float*    score = wf + O_SCORE;
  float*    bufA  = wf + O_BUFA;
  float*    bufB  = wf + O_BUFB;
  float*    bufC  = wf + O_BUFC;
  unsigned* cptr  = wu + O_CPTR;
  float*    q1    = wf + O_Q1;
  float*    q2    = wf + O_Q2;
  float*    smax  = wf + O_SMAX;
  float*    den   = wf + O_DEN;
  float*    av    = wf + O_A;
  float*    bv    = wf + O_B;
  float*    c3    = wf + O_C3;
  float*    fit   = wf + O_FIT;
  unsigned* candA = wu + O_CANDA;
  unsigned* candB = wu + O_CANDB;
  int*      inv   = wi + O_INV;
  unsigned* tptr  = wu + O_TPTR;
  int*      ti    = wi + O_TI;
  int*      tk    = wi + O_TK;
  float*    tv    = wf + O_TV;
  unsigned* tidx  = wu + O_TIDX;
  unsigned* sel   = wu + O_SEL;
  unsigned* perm_i= wu + O_PERM;
  float*    fit_s = wf + O_FITS;
  unsigned* zr    = wu + O_ZR;
  unsigned* cnt   = wu + O_CNT;
  unsigned* cur   = wu + O_CUR;
  unsigned* tcnt  = wu + O_TCNT;
  unsigned* tcur  = wu + O_TCUR;
  unsigned* hist  = wu + O_HIST;
  unsigned* ctrl  = wu + O_CTRL;

  const int TB = 256;
  const int gM = (M_ + TB - 1) / TB;          // 1329
  const int gN = (N_ + TB - 1) / TB;          // 79
  const int gW = (N_ + 3) / 4;                // 5000 (wave-per-node, 4 waves/block)
  const int gG = (N_ + 63) / 64;              // 313 (gemm tiles)
  const int gZ = ((int)(ZR_WORDS > OUT_WORDS ? ZR_WORDS : OUT_WORDS) + TB - 1) / TB;

  hipLaunchKernelGGL(init_k, dim3(gZ), dim3(TB), 0, stream, zr, out);
  hipLaunchKernelGGL(build_edges_k, dim3(gM), dim3(TB), 0, stream, ei, rr, cc, cnt);
  hipLaunchKernelGGL(prefix_k, dim3(1), dim3(1024), 0, stream, cnt, cptr, N_);
  hipLaunchKernelGGL(scatter_eid_k, dim3(gM), dim3(TB), 0, stream, cc, cptr, cur, eid);
  hipLaunchKernelGGL(norm_k, dim3(gM), dim3(TB), 0, stream, rr, cc, cptr, nrm);

  // GCN layer 1: bufA = x@W0 ; bufB = relu(agg + b0)
  hipLaunchKernelGGL((gemm64_k<false>), dim3(gG), dim3(TB), 0, stream, x, W0, nullptr, bufA);
  hipLaunchKernelGGL((agg_k<0>), dim3(gW), dim3(TB), 0, stream, bufA, rr, nrm, cptr, eid, b0, bufB);
  // GCN layer 2: bufA = bufB@W1 ; bufC = relu(agg + b1)   (= x2)
  hipLaunchKernelGGL((gemm64_k<false>), dim3(gG), dim3(TB), 0, stream, bufB, W1, nullptr, bufA);
  hipLaunchKernelGGL((agg_k<0>), dim3(gW), dim3(TB), 0, stream, bufA, rr, nrm, cptr, eid, b1, bufC);

  // attention pooling
  hipLaunchKernelGGL((agg_k<1>), dim3(gW), dim3(TB), 0, stream, bufC, rr, (const float*)nullptr, cptr, eid, (const float*)nullptr, bufA); // x_q raw
  hipLaunchKernelGGL((gemm64_k<true>), dim3(gG), dim3(TB), 0, stream, bufA, linW, linb, bufB);   // x_q lin
  hipLaunchKernelGGL(dots_k, dim3(gW), dim3(TB), 0, stream, bufB, bufC, attW, q1, q2);
  hipLaunchKernelGGL(score_k, dim3(gM), dim3(TB), 0, stream, rr, cc, q1, q2, attb, score);
  hipLaunchKernelGGL(smaxden_k, dim3(gN), dim3(TB), 0, stream, score, cptr, eid, smax, den);
  hipLaunchKernelGGL(scnorm_k, dim3(gM), dim3(TB), 0, stream, cc, smax, den, score);
  hipLaunchKernelGGL((agg_k<2>), dim3(gW), dim3(TB), 0, stream, bufC, rr, score, cptr, eid, (const float*)nullptr, bufA); // xc

  // fitness
  hipLaunchKernelGGL(fitpre_k, dim3(gW), dim3(TB), 0, stream, bufA, le1W, le1b, le2W, le3W, le3b, av, bv, c3);
  hipLaunchKernelGGL(fitness_k, dim3(gN), dim3(TB), 0, stream, cptr, eid, rr, av, bv, c3, fit);

  // exact top-K (3-level radix select on (fbits, ~idx))
  hipLaunchKernelGGL((radix_hist_k<0>), dim3(gN), dim3(TB), 0, stream, fit, (const unsigned*)nullptr, (const unsigned*)nullptr, hist);
  hipLaunchKernelGGL(radix_scan_k, dim3(1), dim3(1024), 0, stream, hist, ctrl);
  hipLaunchKernelGGL((radix_emit_k<0>), dim3(gN), dim3(TB), 0, stream, fit, (const unsigned*)nullptr, (const unsigned*)nullptr, ctrl, sel, candA, &ctrl[2]);
  hipLaunchKernelGGL((radix_hist_k<1>), dim3(gN), dim3(TB), 0, stream, fit, candA, &ctrl[2], hist);
  hipLaunchKernelGGL(radix_scan_k, dim3(1), dim3(1024), 0, stream, hist, ctrl);
  hipLaunchKernelGGL((radix_emit_k<1>), dim3(gN), dim3(TB), 0, stream, fit, candA, &ctrl[2], ctrl, sel, candB, &ctrl[3]);
  hipLaunchKernelGGL((radix_hist_k<2>), dim3(gN), dim3(TB), 0, stream, fit, candB, &ctrl[3], hist);
  hipLaunchKernelGGL(radix_scan_k, dim3(1), dim3(1024), 0, stream, hist, ctrl);
  hipLaunchKernelGGL((radix_emit_k<2>), dim3(gN), dim3(TB), 0, stream, fit, candB, &ctrl[3], ctrl, sel, (unsigned*)nullptr, (unsigned*)nullptr);

  hipLaunchKernelGGL(fill_inv_k, dim3(gN), dim3(TB), 0, stream, inv);
  hipLaunchKernelGGL(sort_sel_k, dim3(1), dim3(K_), 0, stream, sel, fit, perm_i, fit_s, out + K_ * F_ + K_ * K_, inv);
  hipLaunchKernelGGL(xnew_k, dim3((K_ * F_) / TB), dim3(TB), 0, stream, bufA, perm_i, fit_s, out);

  // sparse S triplets -> A_new
  hipLaunchKernelGGL(trip_build_k, dim3(gM), dim3(TB), 0, stream, rr, cc, inv, score, ti, tk, tv, tcnt, ctrl);
  hipLaunchKernelGGL(prefix_k, dim3(1), dim3(1024), 0, stream, tcnt, tptr, N_);
  hipLaunchKernelGGL(trip_scatter_k, dim3(TCAP / TB), dim3(TB), 0, stream, ti, tptr, tcur, tidx, ctrl);
  hipLaunchKernelGGL(anew_k, dim3(gM), dim3(TB), 0, stream, rr, cc, tptr, tidx, tk, tv, out + K_ * F_);
  hipLaunchKernelGGL(adiag_k, dim3(1), dim3(TB), 0, stream, out + K_ * F_);

  (void)in_sizes; (void)n_in; (void)out_size; (void)ws_size;
}

// Round 2
// 520.214 us; speedup vs baseline: 1.3472x; 1.3472x over previous
//
#include <hip/hip_runtime.h>
#include <math.h>

// ---------------------------------------------------------------------------
// ASAP pooling block, fixed shapes.
// ---------------------------------------------------------------------------
constexpr int N_ = 20000;
constexpr int E_ = 320000;
constexpr int M_ = E_ + N_;      // edges incl. self loops
constexpr int F_ = 64;
constexpr int K_ = 256;
constexpr int TCAP = 32768;      // S-triplet capacity (expected ~4400)
constexpr int OUT_WORDS = K_ * F_ + K_ * K_ + K_;   // 82176

// ---- workspace layout (word offsets) --------------------------------------
constexpr size_t O_RR   = 0;
constexpr size_t O_CC   = O_RR + M_;
constexpr size_t O_CSRC = O_CC + M_;                   // CSR(by col) source node
constexpr size_t O_CNRM = O_CSRC + M_;                 // CSR gcn norm weight
constexpr size_t O_SC   = O_CNRM + M_;                 // CSR attention score
constexpr size_t O_BUFA = O_SC + M_;
constexpr size_t O_BUFB = O_BUFA + (size_t)N_ * F_;
constexpr size_t O_BUFC = O_BUFB + (size_t)N_ * F_;
constexpr size_t O_CPTR = O_BUFC + (size_t)N_ * F_;    // N+1
constexpr size_t O_Q1   = O_CPTR + N_ + 1;
constexpr size_t O_Q2   = O_Q1 + N_;
constexpr size_t O_AV   = O_Q2 + N_;
constexpr size_t O_BV   = O_AV + N_;
constexpr size_t O_C3   = O_BV + N_;
constexpr size_t O_FIT  = O_C3 + N_;
constexpr size_t O_TPTR = O_FIT + N_;                  // N+1
constexpr size_t O_TI   = O_TPTR + N_ + 1;
constexpr size_t O_TK   = O_TI + TCAP;
constexpr size_t O_TV   = O_TK + TCAP;
constexpr size_t O_TIDX = O_TV + TCAP;
constexpr size_t O_PERM = O_TIDX + TCAP;               // 256 (uint)
constexpr size_t O_FITS = O_PERM + K_;                 // 256 (f32)
// zero-initialized region:
constexpr size_t O_ZR   = O_FITS + K_;
constexpr size_t O_CNT  = O_ZR;                        // N (in-degree counts)
constexpr size_t O_CUR  = O_CNT + N_;                  // N
constexpr size_t O_TCNT = O_CUR + N_;                  // N
constexpr size_t O_TCUR = O_TCNT + N_;                 // N
constexpr size_t O_CTRL = O_TCUR + N_;                 // 8 (ctrl[5]=trip count)
constexpr size_t ZR_WORDS = O_CTRL + 8 - O_ZR;

// ---------------------------------------------------------------------------
__global__ void init_k(unsigned* __restrict__ zr, float* __restrict__ dout) {
  int g = blockIdx.x * blockDim.x + threadIdx.x;
  if (g < (int)ZR_WORDS) zr[g] = 0u;
  if (g < OUT_WORDS) dout[g] = 0.0f;
}

__global__ void build_edges_k(const int* __restrict__ ei, int* __restrict__ rr,
                              int* __restrict__ cc, unsigned* __restrict__ cnt) {
  int g = blockIdx.x * blockDim.x + threadIdx.x;
  if (g >= M_) return;
  int r, c;
  if (g < E_) { r = ei[g]; c = ei[E_ + g]; } else { r = g - E_; c = r; }
  rr[g] = r; cc[g] = c;
  atomicAdd(&cnt[c], 1u);
}

// single-block exclusive prefix (n bins -> ptr[n+1])
__global__ void prefix_k(const unsigned* __restrict__ cnt, unsigned* __restrict__ ptr, int n) {
  __shared__ unsigned part[1024];
  int t = threadIdx.x;
  int chunk = (n + 1023) >> 10;
  int i0 = t * chunk;
  unsigned s = 0;
  for (int j = 0; j < chunk; ++j) { int i = i0 + j; if (i < n) s += cnt[i]; }
  part[t] = s; __syncthreads();
  for (int off = 1; off < 1024; off <<= 1) {
    unsigned v = (t >= off) ? part[t - off] : 0u;
    __syncthreads();
    part[t] += v;
    __syncthreads();
  }
  unsigned run = part[t] - s;
  for (int j = 0; j < chunk; ++j) {
    int i = i0 + j;
    if (i < n) { ptr[i] = run; run += cnt[i]; }
  }
  if (t == 0) ptr[n] = part[1023];
}

// scatter edge -> CSR(by col) position; store src node and gcn norm weight
__global__ void scatter_csr_k(const int* __restrict__ rr, const int* __restrict__ cc,
                              const unsigned* __restrict__ cptr, unsigned* __restrict__ cur,
                              int* __restrict__ csrc, float* __restrict__ cnrm) {
  int g = blockIdx.x * blockDim.x + threadIdx.x;
  if (g >= M_) return;
  int r = rr[g], c = cc[g];
  unsigned pos = cptr[c] + atomicAdd(&cur[c], 1u);
  csrc[pos] = r;
  float dr = (float)(cptr[r + 1] - cptr[r]);
  float dc = (float)(cptr[c + 1] - cptr[c]);
  cnrm[pos] = (1.0f / sqrtf(dr)) * (1.0f / sqrtf(dc));
}

// Y[n,64] = X[n,64] @ W[64,64].  OUT=0: Y only. OUT=1: Y+bias. OUT=2: no Y,
// q1[r] = ((X@W)[r,:]+bias)·attW[0:64]  (wave-reduce epilogue).
template<int OUT>
__global__ void gemm64_k(const float* __restrict__ X, const float* __restrict__ W,
                         const float* __restrict__ bias, float* __restrict__ Y,
                         const float* __restrict__ attW, float* __restrict__ q1) {
  __shared__ float xs[64][64];
  __shared__ float wsh[64][64];
  int t = threadIdx.x;
  int r0 = blockIdx.x * 64;
  for (int i = 0; i < 16; ++i) {
    int idx = t + i * 256;
    wsh[idx >> 6][idx & 63] = W[idx];
  }
  for (int i = 0; i < 16; ++i) {
    int idx = t + i * 256;
    int r = idx >> 6, c = idx & 63;
    xs[r][c] = (r0 + r < N_) ? X[(size_t)(r0 + r) * F_ + c] : 0.0f;
  }
  __syncthreads();
  int c = t & 63, rg = t >> 6;
  float acc[16];
#pragma unroll
  for (int m = 0; m < 16; ++m) acc[m] = 0.0f;
  for (int k = 0; k < 64; ++k) {
    float w = wsh[k][c];
#pragma unroll
    for (int m = 0; m < 16; ++m) acc[m] += xs[rg + 4 * m][k] * w;
  }
  float bv = (OUT >= 1) ? bias[c] : 0.0f;
  if (OUT == 2) {
    float aw = attW[c];
#pragma unroll
    for (int m = 0; m < 16; ++m) {
      float v = (acc[m] + bv) * aw;
      for (int off = 32; off; off >>= 1) v += __shfl_down(v, off);
      int r = r0 + rg + 4 * m;
      if (c == 0 && r < N_) q1[r] = v;
    }
  } else {
    for (int m = 0; m < 16; ++m) {
      int r = r0 + rg + 4 * m;
      if (r < N_) Y[(size_t)r * F_ + c] = acc[m] + bv;
    }
  }
}

// MODE 0: weighted sum + bias + relu (GCN). MODE 1: max. MODE 2: weighted sum.
// EPI 1: q2[i] = acc·attW[64:128].  EPI 2: av/bv/c3 dots with le*W.
// one wave per node, lane = feature.
template<int MODE, int EPI>
__global__ void agg_k(const float* __restrict__ H, const int* __restrict__ csrc,
                      const float* __restrict__ wts, const unsigned* __restrict__ cptr,
                      const float* __restrict__ bias, float* __restrict__ Y,
                      const float* __restrict__ attW, float* __restrict__ q2,
                      const float* __restrict__ le1W, const float* __restrict__ le1b,
                      const float* __restrict__ le2W, const float* __restrict__ le3W,
                      const float* __restrict__ le3b, float* __restrict__ av,
                      float* __restrict__ bv, float* __restrict__ c3) {
  int wid = blockIdx.x * (blockDim.x >> 6) + (threadIdx.x >> 6);
  int lane = threadIdx.x & 63;
  if (wid >= N_) return;
  unsigned p0 = cptr[wid], p1 = cptr[wid + 1];
  float acc = (MODE == 1) ? -INFINITY : 0.0f;
  for (unsigned p = p0; p < p1; ++p) {
    int s = csrc[p];
    float h = H[(size_t)s * F_ + lane];
    if (MODE == 1) acc = fmaxf(acc, h);
    else           acc += wts[p] * h;
  }
  if (MODE == 0) acc = fmaxf(acc + bias[lane], 0.0f);
  Y[(size_t)wid * F_ + lane] = acc;
  if (EPI == 1) {
    float v = acc * attW[64 + lane];
    for (int off = 32; off; off >>= 1) v += __shfl_down(v, off);
    if (lane == 0) q2[wid] = v;
  }
  if (EPI == 2) {
    float s1 = acc * le1W[lane], s2 = acc * le2W[lane], s3 = acc * le3W[lane];
    for (int off = 32; off; off >>= 1) {
      s1 += __shfl_down(s1, off);
      s2 += __shfl_down(s2, off);
      s3 += __shfl_down(s3, off);
    }
    if (lane == 0) { av[wid] = s1 + le1b[0]; bv[wid] = s2; c3[wid] = s3 + le3b[0]; }
  }
}

// fused leaky-score + segment max + exp-sum + normalize, thread per node (CSR)
__global__ void attn_sc_k(const int* __restrict__ csrc, const unsigned* __restrict__ cptr,
                          const float* __restrict__ q1, const float* __restrict__ q2,
                          const float* __restrict__ attb, float* __restrict__ sc) {
  int i = blockIdx.x * blockDim.x + threadIdx.x;
  if (i >= N_) return;
  unsigned p0 = cptr[i], p1 = cptr[i + 1];
  float base = q1[i] + attb[0];
  float m = -INFINITY;
  for (unsigned p = p0; p < p1; ++p) {
    float s = base + q2[csrc[p]];
    s = (s > 0.0f) ? s : 0.2f * s;
    sc[p] = s;
    m = fmaxf(m, s);
  }
  float d = 0.0f;
  for (unsigned p = p0; p < p1; ++p) {
    float e = expf(sc[p] - m);
    sc[p] = e;
    d += e;
  }
  for (unsigned p = p0; p < p1; ++p) sc[p] = sc[p] / d;
}

__global__ void fitness_k(const unsigned* __restrict__ cptr, const int* __restrict__ csrc,
                          const float* __restrict__ av, const float* __restrict__ bv,
                          const float* __restrict__ c3, float* __restrict__ fit) {
  int i = blockIdx.x * blockDim.x + threadIdx.x;
  if (i >= N_) return;
  unsigned p0 = cptr[i], p1 = cptr[i + 1];
  float s = 0.0f;
  for (unsigned p = p0; p < p1; ++p) s += av[csrc[p]];
  float deg = (float)(p1 - p0);
  float val = s - deg * bv[i] + c3[i];
  fit[i] = 1.0f / (1.0f + expf(-val));
}

// ---------------------------------------------------------------------------
// Single-block exact top-K: 4x8-bit radix select on float bits (all values >0
// so raw-bit order == value order), exact smallest-index tie-break via 2-level
// radix on index bits, bitonic sort of the 256 winners, outputs perm/fit/inv.
// ---------------------------------------------------------------------------
__global__ __launch_bounds__(1024) void topk_k(const float* __restrict__ fit,
                                               unsigned* __restrict__ perm_i,
                                               float* __restrict__ fit_s,
                                               float* __restrict__ out_perm) {
  __shared__ unsigned hist[256 * 8];
  __shared__ unsigned long long keys[K_];
  __shared__ unsigned s_pfx, s_rem, s_cnt, s_bstar, s_rem2, s_cut;
  int t = threadIdx.x;
  int sub = t & 7;

  unsigned msk = 0, pfx = 0, rem = K_;
  for (int lvl = 0; lvl < 4; ++lvl) {
    int shift = 24 - lvl * 8;
    for (int i = t; i < 256 * 8; i += 1024) hist[i] = 0;
    __syncthreads();
    for (int i = t; i < N_; i += 1024) {
      unsigned fb = __float_as_uint(fit[i]);
      if ((fb & msk) == pfx)
        atomicAdd(&hist[(((fb >> shift) & 0xFF) << 3) + sub], 1u);
    }
    __syncthreads();
    if (t == 0) {
      unsigned run = 0;
      for (int b = 255; b >= 0; --b) {
        unsigned h = 0;
        for (int s = 0; s < 8; ++s) h += hist[(b << 3) + s];
        run += h;
        if (run >= rem) {
          s_pfx = pfx | ((unsigned)b << shift);
          s_rem = rem - (run - h);
          break;
        }
      }
    }
    __syncthreads();
    pfx = s_pfx; rem = s_rem; msk |= (0xFFu << shift);
    __syncthreads();
  }
  // pfx == exact threshold bits; rem = how many ties (fb==pfx) to take,
  // preferring smallest index.
  if (t == 0) s_cnt = 0;
  __syncthreads();
  for (int i = t; i < N_; i += 1024) {
    unsigned fb = __float_as_uint(fit[i]);
    if (fb > pfx) {
      unsigned j = atomicAdd(&s_cnt, 1u);
      keys[j] = ((unsigned long long)fb << 32) | (unsigned long long)(0xFFFFFFFFu - (unsigned)i);
    }
  }
  __syncthreads();
  if (rem > 0) {
    // tie level A: bins = idx >> 7
    for (int i = t; i < 256 * 8; i += 1024) hist[i] = 0;
    __syncthreads();
    for (int i = t; i < N_; i += 1024)
      if (__float_as_uint(fit[i]) == pfx) atomicAdd(&hist[((i >> 7) << 3) + sub], 1u);
    __syncthreads();
    if (t == 0) {
      unsigned run = 0;
      for (int b = 0; b < 256; ++b) {
        unsigned h = 0;
        for (int s = 0; s < 8; ++s) h += hist[(b << 3) + s];
        if (run + h >= rem) { s_bstar = (unsigned)b; s_rem2 = rem - run; break; }
        run += h;
      }
    }
    __syncthreads();
    unsigned bstar = s_bstar, rem2 = s_rem2;
    // tie level B: bins = idx & 127 within bstar (unique indices -> h in {0,1})
    for (int i = t; i < 256 * 8; i += 1024) hist[i] = 0;
    __syncthreads();
    for (int i = t; i < N_; i += 1024)
      if (__float_as_uint(fit[i]) == pfx && (unsigned)(i >> 7) == bstar)
        atomicAdd(&hist[((i & 127) << 3) + sub], 1u);
    __syncthreads();
    if (t == 0) {
      unsigned run = 0;
      for (int b = 0; b < 128; ++b) {
        unsigned h = 0;
        for (int s = 0; s < 8; ++s) h += hist[(b << 3) + s];
        if (run + h >= rem2) { s_cut = (unsigned)b; break; }
        run += h;
      }
    }
    __syncthreads();
    unsigned cut = s_cut;
    for (int i = t; i < N_; i += 1024) {
      if (__float_as_uint(fit[i]) == pfx) {
        unsigned hi = (unsigned)(i >> 7);
        if (hi < bstar || (hi == bstar && (unsigned)(i & 127) <= cut)) {
          unsigned j = atomicAdd(&s_cnt, 1u);
          keys[j] = ((unsigned long long)pfx << 32) | (unsigned long long)(0xFFFFFFFFu - (unsigned)i);
        }
      }
    }
    __syncthreads();
  }
  // bitonic sort 256 keys descending -> (fit desc, idx asc)
  for (unsigned k = 2; k <= (unsigned)K_; k <<= 1) {
    for (unsigned j = k >> 1; j > 0; j >>= 1) {
      unsigned long long nv = 0;
      if (t < K_) {
        unsigned partner = (unsigned)t ^ j;
        unsigned long long a = keys[t], b = keys[partner];
        bool desc = ((t & k) == 0);
        bool tFirst = ((unsigned)t < partner);
        unsigned long long mx = (a > b) ? a : b;
        unsigned long long mn = (a > b) ? b : a;
        nv = (desc == tFirst) ? mx : mn;
      }
      __syncthreads();
      if (t < K_) keys[t] = nv;
      __syncthreads();
    }
  }
  if (t < K_) {
    unsigned long long kk = keys[t];
    unsigned idx = 0xFFFFFFFFu - (unsigned)(kk & 0xFFFFFFFFu);
    perm_i[t] = idx;
    fit_s[t] = __uint_as_float((unsigned)(kk >> 32));
    out_perm[t] = (float)idx;
  }
}

__global__ void xnew_k(const float* __restrict__ XC, const unsigned* __restrict__ perm_i,
                       const float* __restrict__ fit_s, float* __restrict__ out) {
  int g = blockIdx.x * blockDim.x + threadIdx.x;
  if (g >= K_ * F_) return;
  int k = g >> 6, f = g & 63;
  out[g] = XC[(size_t)perm_i[k] * F_ + f] * fit_s[k];
}

// build S triplets directly from the 256 selected nodes' CSR ranges
__global__ void trip_sel_k(const unsigned* __restrict__ perm_i, const unsigned* __restrict__ cptr,
                           const int* __restrict__ csrc, const float* __restrict__ sc,
                           int* __restrict__ ti, int* __restrict__ tk, float* __restrict__ tv,
                           unsigned* __restrict__ tcnt, unsigned* __restrict__ ctrl) {
  int k = blockIdx.x * blockDim.x + threadIdx.x;
  if (k >= K_) return;
  unsigned i = perm_i[k];
  unsigned p0 = cptr[i], p1 = cptr[i + 1];
  for (unsigned p = p0; p < p1; ++p) {
    unsigned j = atomicAdd(&ctrl[5], 1u);
    if (j < (unsigned)TCAP) {
      int r = csrc[p];
      ti[j] = r; tk[j] = k; tv[j] = sc[p];
      atomicAdd(&tcnt[r], 1u);
    }
  }
}

__global__ void trip_scatter_k(const int* __restrict__ ti, const unsigned* __restrict__ tptr,
                               unsigned* __restrict__ tcur, unsigned* __restrict__ tidx,
                               const unsigned* __restrict__ ctrl) {
  int g = blockIdx.x * blockDim.x + threadIdx.x;
  unsigned cnt = ctrl[5]; if (cnt > (unsigned)TCAP) cnt = TCAP;
  if (g >= (int)cnt) return;
  int i = ti[g];
  unsigned pos = tptr[i] + atomicAdd(&tcur[i], 1u);
  tidx[pos] = (unsigned)g;
}

// A[k1,k2] += sum over edges of S[row,k1]*S[col,k2]  (triplet pair expansion)
__global__ void anew_k(const int* __restrict__ rr, const int* __restrict__ cc,
                       const unsigned* __restrict__ tptr, const unsigned* __restrict__ tidx,
                       const int* __restrict__ tk, const float* __restrict__ tv,
                       float* __restrict__ A) {
  int g = blockIdx.x * blockDim.x + threadIdx.x;
  if (g >= M_) return;
  int i = rr[g], j = cc[g];
  unsigned a0 = tptr[i], a1 = tptr[i + 1];
  if (a0 == a1) return;
  unsigned b0 = tptr[j], b1 = tptr[j + 1];
  if (b0 == b1) return;
  for (unsigned pa = a0; pa < a1; ++pa) {
    unsigned ta = tidx[pa];
    int k1 = tk[ta];
    float va = tv[ta];
    float* Arow = A + (size_t)k1 * K_;
    for (unsigned pb = b0; pb < b1; ++pb) {
      unsigned tb = tidx[pb];
      atomicAdd(&Arow[tk[tb]], va * tv[tb]);
    }
  }
}

__global__ void adiag_k(float* __restrict__ A) {
  int t = threadIdx.x;
  if (t < K_) A[(size_t)t * K_ + t] = 1.0f;
}

// ---------------------------------------------------------------------------
extern "C" void kernel_launch(void* const* d_in, const int* in_sizes, int n_in,
                              void* d_out, int out_size, void* d_ws, size_t ws_size,
                              hipStream_t stream) {
  const float* x     = (const float*)d_in[0];
  const int*   ei    = (const int*)d_in[1];
  const float* W0    = (const float*)d_in[2];
  const float* b0    = (const float*)d_in[3];
  const float* W1    = (const float*)d_in[4];
  const float* b1    = (const float*)d_in[5];
  const float* linW  = (const float*)d_in[6];
  const float* linb  = (const float*)d_in[7];
  const float* attW  = (const float*)d_in[8];
  const float* attb  = (const float*)d_in[9];
  const float* le1W  = (const float*)d_in[10];
  const float* le1b  = (const float*)d_in[11];
  const float* le2W  = (const float*)d_in[12];
  const float* le3W  = (const float*)d_in[13];
  const float* le3b  = (const float*)d_in[14];

  float*    wf = (float*)d_ws;
  unsigned* wu = (unsigned*)d_ws;
  int*      wi = (int*)d_ws;
  float*    out = (float*)d_out;

  int*      rr    = wi + O_RR;
  int*      cc    = wi + O_CC;
  int*      csrc  = wi + O_CSRC;
  float*    cnrm  = wf + O_CNRM;
  float*    sc    = wf + O_SC;
  float*    bufA  = wf + O_BUFA;
  float*    bufB  = wf + O_BUFB;
  float*    bufC  = wf + O_BUFC;
  unsigned* cptr  = wu + O_CPTR;
  float*    q1    = wf + O_Q1;
  float*    q2    = wf + O_Q2;
  float*    av    = wf + O_AV;
  float*    bv    = wf + O_BV;
  float*    c3    = wf + O_C3;
  float*    fit   = wf + O_FIT;
  unsigned* tptr  = wu + O_TPTR;
  int*      ti    = wi + O_TI;
  int*      tk    = wi + O_TK;
  float*    tv    = wf + O_TV;
  unsigned* tidx  = wu + O_TIDX;
  unsigned* perm_i= wu + O_PERM;
  float*    fit_s = wf + O_FITS;
  unsigned* zr    = wu + O_ZR;
  unsigned* cnt   = wu + O_CNT;
  unsigned* cur   = wu + O_CUR;
  unsigned* tcnt  = wu + O_TCNT;
  unsigned* tcur  = wu + O_TCUR;
  unsigned* ctrl  = wu + O_CTRL;

  const int TB = 256;
  const int gM = (M_ + TB - 1) / TB;          // 1329
  const int gN = (N_ + TB - 1) / TB;          // 79
  const int gW = (N_ + 3) / 4;                // 5000 (wave-per-node, 4 waves/block)
  const int gG = (N_ + 63) / 64;              // 313 (gemm tiles)
  const int gZ = ((int)(ZR_WORDS > OUT_WORDS ? ZR_WORDS : OUT_WORDS) + TB - 1) / TB;

  hipLaunchKernelGGL(init_k, dim3(gZ), dim3(TB), 0, stream, zr, out);
  hipLaunchKernelGGL(build_edges_k, dim3(gM), dim3(TB), 0, stream, ei, rr, cc, cnt);
  hipLaunchKernelGGL(prefix_k, dim3(1), dim3(1024), 0, stream, cnt, cptr, N_);
  hipLaunchKernelGGL(scatter_csr_k, dim3(gM), dim3(TB), 0, stream, rr, cc, cptr, cur, csrc, cnrm);

  // GCN layer 1: bufA = x@W0 ; bufB = relu(agg + b0)
  hipLaunchKernelGGL((gemm64_k<0>), dim3(gG), dim3(TB), 0, stream, x, W0, nullptr, bufA, nullptr, nullptr);
  hipLaunchKernelGGL((agg_k<0, 0>), dim3(gW), dim3(TB), 0, stream, bufA, csrc, cnrm, cptr, b0, bufB,
                     nullptr, nullptr, nullptr, nullptr, nullptr, nullptr, nullptr, nullptr, nullptr, nullptr);
  // GCN layer 2: bufA = bufB@W1 ; bufC = relu(agg + b1) = x2 ; q2 epilogue
  hipLaunchKernelGGL((gemm64_k<0>), dim3(gG), dim3(TB), 0, stream, bufB, W1, nullptr, bufA, nullptr, nullptr);
  hipLaunchKernelGGL((agg_k<0, 1>), dim3(gW), dim3(TB), 0, stream, bufA, csrc, cnrm, cptr, b1, bufC,
                     attW, q2, nullptr, nullptr, nullptr, nullptr, nullptr, nullptr, nullptr, nullptr);

  // attention pooling: x_q = segment_max -> lin (q1 dot only) -> scores -> xc
  hipLaunchKernelGGL((agg_k<1, 0>), dim3(gW), dim3(TB), 0, stream, bufC, csrc, (const float*)nullptr, cptr,
                     (const float*)nullptr, bufA, nullptr, nullptr, nullptr, nullptr, nullptr, nullptr, nullptr,
                     nullptr, nullptr, nullptr);
  hipLaunchKernelGGL((gemm64_k<2>), dim3(gG), dim3(TB), 0, stream, bufA, linW, linb, nullptr, attW, q1);
  hipLaunchKernelGGL(attn_sc_k, dim3(gN), dim3(TB), 0, stream, csrc, cptr, q1, q2, attb, sc);
  hipLaunchKernelGGL((agg_k<2, 2>), dim3(gW), dim3(TB), 0, stream, bufC, csrc, sc, cptr,
                     (const float*)nullptr, bufB, nullptr, nullptr, le1W, le1b, le2W, le3W, le3b, av, bv, c3);

  // fitness + exact top-K
  hipLaunchKernelGGL(fitness_k, dim3(gN), dim3(TB), 0, stream, cptr, csrc, av, bv, c3, fit);
  hipLaunchKernelGGL(topk_k, dim3(1), dim3(1024), 0, stream, fit, perm_i, fit_s, out + K_ * F_ + K_ * K_);
  hipLaunchKernelGGL(xnew_k, dim3((K_ * F_) / TB), dim3(TB), 0, stream, bufB, perm_i, fit_s, out);

  // sparse S triplets -> A_new
  hipLaunchKernelGGL(trip_sel_k, dim3(1), dim3(TB), 0, stream, perm_i, cptr, csrc, sc, ti, tk, tv, tcnt, ctrl);
  hipLaunchKernelGGL(prefix_k, dim3(1), dim3(1024), 0, stream, tcnt, tptr, N_);
  hipLaunchKernelGGL(trip_scatter_k, dim3(TCAP / TB), dim3(TB), 0, stream, ti, tptr, tcur, tidx, ctrl);
  hipLaunchKernelGGL(anew_k, dim3(gM), dim3(TB), 0, stream, rr, cc, tptr, tidx, tk, tv, out + K_ * F_);
  hipLaunchKernelGGL(adiag_k, dim3(1), dim3(TB), 0, stream, out + K_ * F_);

  (void)in_sizes; (void)n_in; (void)out_size; (void)ws_size;
}

// Round 3
// 449.199 us; speedup vs baseline: 1.5601x; 1.1581x over previous
//
#include <hip/hip_runtime.h>
#include <math.h>

// ---------------------------------------------------------------------------
// ASAP pooling block, fixed shapes.
// ---------------------------------------------------------------------------
constexpr int N_ = 20000;
constexpr int E_ = 320000;
constexpr int M_ = E_ + N_;      // edges incl. self loops
constexpr int F_ = 64;
constexpr int K_ = 256;
constexpr int TCAP = 32768;      // S-triplet capacity (expected ~4400)
constexpr int OUT_WORDS = K_ * F_ + K_ * K_ + K_;   // 82176

// ---- workspace layout (word offsets) --------------------------------------
constexpr size_t O_RR   = 0;
constexpr size_t O_CC   = O_RR + M_;
constexpr size_t O_CSRC = O_CC + M_;                   // CSR(by col) source node
constexpr size_t O_CNRM = O_CSRC + M_;                 // CSR gcn norm weight
constexpr size_t O_SC   = O_CNRM + M_;                 // CSR attention exp(score)
constexpr size_t O_BUFA = O_SC + M_;
constexpr size_t O_BUFB = O_BUFA + (size_t)N_ * F_;
constexpr size_t O_BUFC = O_BUFB + (size_t)N_ * F_;
constexpr size_t O_CPTR = O_BUFC + (size_t)N_ * F_;    // N+1
constexpr size_t O_Q1   = O_CPTR + N_ + 1;
constexpr size_t O_Q2   = O_Q1 + N_;
constexpr size_t O_DEN  = O_Q2 + N_;
constexpr size_t O_AV   = O_DEN + N_;
constexpr size_t O_BV   = O_AV + N_;
constexpr size_t O_C3   = O_BV + N_;
constexpr size_t O_FIT  = O_C3 + N_;
constexpr size_t O_TPTR = O_FIT + N_;                  // N+1
constexpr size_t O_TI   = O_TPTR + N_ + 1;
constexpr size_t O_TK   = O_TI + TCAP;
constexpr size_t O_TV   = O_TK + TCAP;
constexpr size_t O_TIDX = O_TV + TCAP;
constexpr size_t O_PERM = O_TIDX + TCAP;               // 256 (uint)
constexpr size_t O_FITS = O_PERM + K_;                 // 256 (f32)
constexpr size_t O_WQ   = O_FITS + K_;                 // 65 (lin/att folded vec + bias)
// zero-initialized region:
constexpr size_t O_ZR   = O_WQ + 72;
constexpr size_t O_CNT  = O_ZR;                        // N (in-degree counts)
constexpr size_t O_CUR  = O_CNT + N_;                  // N
constexpr size_t O_TCNT = O_CUR + N_;                  // N
constexpr size_t O_TCUR = O_TCNT + N_;                 // N
constexpr size_t O_CTRL = O_TCUR + N_;                 // 8 (ctrl[5]=trip count)
constexpr size_t ZR_WORDS = O_CTRL + 8 - O_ZR;

// ---------------------------------------------------------------------------
__global__ void init_k(unsigned* __restrict__ zr, float* __restrict__ dout) {
  int g = blockIdx.x * blockDim.x + threadIdx.x;
  if (g < (int)ZR_WORDS) zr[g] = 0u;
  if (g < OUT_WORDS) dout[g] = 0.0f;
}

__global__ void build_edges_k(const int* __restrict__ ei, int* __restrict__ rr,
                              int* __restrict__ cc, unsigned* __restrict__ cnt) {
  int g = blockIdx.x * blockDim.x + threadIdx.x;
  if (g >= M_) return;
  int r, c;
  if (g < E_) { r = ei[g]; c = ei[E_ + g]; } else { r = g - E_; c = r; }
  rr[g] = r; cc[g] = c;
  atomicAdd(&cnt[c], 1u);
}

// single-block exclusive prefix (n bins -> ptr[n+1])
__global__ void prefix_k(const unsigned* __restrict__ cnt, unsigned* __restrict__ ptr, int n) {
  __shared__ unsigned part[1024];
  int t = threadIdx.x;
  int chunk = (n + 1023) >> 10;
  int i0 = t * chunk;
  unsigned s = 0;
  for (int j = 0; j < chunk; ++j) { int i = i0 + j; if (i < n) s += cnt[i]; }
  part[t] = s; __syncthreads();
  for (int off = 1; off < 1024; off <<= 1) {
    unsigned v = (t >= off) ? part[t - off] : 0u;
    __syncthreads();
    part[t] += v;
    __syncthreads();
  }
  unsigned run = part[t] - s;
  for (int j = 0; j < chunk; ++j) {
    int i = i0 + j;
    if (i < n) { ptr[i] = run; run += cnt[i]; }
  }
  if (t == 0) ptr[n] = part[1023];
}

// scatter edge -> CSR(by col) position; store src node and gcn norm weight
__global__ void scatter_csr_k(const int* __restrict__ rr, const int* __restrict__ cc,
                              const unsigned* __restrict__ cptr, unsigned* __restrict__ cur,
                              int* __restrict__ csrc, float* __restrict__ cnrm) {
  int g = blockIdx.x * blockDim.x + threadIdx.x;
  if (g >= M_) return;
  int r = rr[g], c = cc[g];
  unsigned pos = cptr[c] + atomicAdd(&cur[c], 1u);
  csrc[pos] = r;
  float dr = (float)(cptr[r + 1] - cptr[r]);
  float dc = (float)(cptr[c + 1] - cptr[c]);
  cnrm[pos] = (1.0f / sqrtf(dr)) * (1.0f / sqrtf(dc));
}

// Y[n,64] = X[n,64] @ W[64,64]. Tiled: 64 rows/block, 256 threads.
__global__ void gemm64_k(const float* __restrict__ X, const float* __restrict__ W,
                         float* __restrict__ Y) {
  __shared__ float xs[64][64];
  __shared__ float wsh[64][64];
  int t = threadIdx.x;
  int r0 = blockIdx.x * 64;
  for (int i = 0; i < 16; ++i) {
    int idx = t + i * 256;
    wsh[idx >> 6][idx & 63] = W[idx];
  }
  for (int i = 0; i < 16; ++i) {
    int idx = t + i * 256;
    int r = idx >> 6, c = idx & 63;
    xs[r][c] = (r0 + r < N_) ? X[(size_t)(r0 + r) * F_ + c] : 0.0f;
  }
  __syncthreads();
  int c = t & 63, rg = t >> 6;
  float acc[16];
#pragma unroll
  for (int m = 0; m < 16; ++m) acc[m] = 0.0f;
  for (int k = 0; k < 64; ++k) {
    float w = wsh[k][c];
#pragma unroll
    for (int m = 0; m < 16; ++m) acc[m] += xs[rg + 4 * m][k] * w;
  }
  for (int m = 0; m < 16; ++m) {
    int r = r0 + rg + 4 * m;
    if (r < N_) Y[(size_t)r * F_ + c] = acc[m];
  }
}

// wq[f] = sum_c linW[f][c]*attW[c] ; wq[64] = sum_c linb[c]*attW[c]. 1 wave.
__global__ void wq_k(const float* __restrict__ linW, const float* __restrict__ linb,
                     const float* __restrict__ attW, float* __restrict__ wq) {
  int f = threadIdx.x;   // 64 threads
  float s = 0.0f;
  for (int c = 0; c < 64; ++c) s += linW[f * 64 + c] * attW[c];
  wq[f] = s;
  float b = linb[f] * attW[f];
  for (int off = 32; off; off >>= 1) b += __shfl_down(b, off);
  if (f == 0) wq[64] = b;
}

// MODE 0: weighted sum + bias + relu (GCN). MODE 1: max. MODE 2: weighted sum.
// DIV: acc /= den[node] after loop (deferred softmax normalize).
// EPI 1: outA[i] = acc·vecA[64..127].  EPI 2: av/bv/c3 dots. EPI 3: outA[i]=acc·vecA[0..63]+vecA[64].
// one wave per node, lane = feature.
template<int MODE, int EPI, bool WRITEY, bool DIV>
__global__ void agg_k(const float* __restrict__ H, const int* __restrict__ csrc,
                      const float* __restrict__ wts, const unsigned* __restrict__ cptr,
                      const float* __restrict__ bias, float* __restrict__ Y,
                      const float* __restrict__ vecA, float* __restrict__ outA,
                      const float* __restrict__ le1W, const float* __restrict__ le1b,
                      const float* __restrict__ le2W, const float* __restrict__ le3W,
                      const float* __restrict__ le3b, float* __restrict__ av,
                      float* __restrict__ bv, float* __restrict__ c3,
                      const float* __restrict__ den) {
  int wid = blockIdx.x * (blockDim.x >> 6) + (threadIdx.x >> 6);
  int lane = threadIdx.x & 63;
  if (wid >= N_) return;
  unsigned p0 = cptr[wid], p1 = cptr[wid + 1];
  float acc = (MODE == 1) ? -INFINITY : 0.0f;
  for (unsigned p = p0; p < p1; ++p) {
    int s = csrc[p];
    float h = H[(size_t)s * F_ + lane];
    if (MODE == 1) acc = fmaxf(acc, h);
    else           acc += wts[p] * h;
  }
  if (MODE == 0) acc = fmaxf(acc + bias[lane], 0.0f);
  if (DIV) acc /= den[wid];
  if (WRITEY) Y[(size_t)wid * F_ + lane] = acc;
  if (EPI == 1) {
    float v = acc * vecA[64 + lane];
    for (int off = 32; off; off >>= 1) v += __shfl_down(v, off);
    if (lane == 0) outA[wid] = v;
  }
  if (EPI == 3) {
    float v = acc * vecA[lane];
    for (int off = 32; off; off >>= 1) v += __shfl_down(v, off);
    if (lane == 0) outA[wid] = v + vecA[64];
  }
  if (EPI == 2) {
    float s1 = acc * le1W[lane], s2 = acc * le2W[lane], s3 = acc * le3W[lane];
    for (int off = 32; off; off >>= 1) {
      s1 += __shfl_down(s1, off);
      s2 += __shfl_down(s2, off);
      s3 += __shfl_down(s3, off);
    }
    if (lane == 0) { av[wid] = s1 + le1b[0]; bv[wid] = s2; c3[wid] = s3 + le3b[0]; }
  }
}

// fused leaky-score + segment max + exp; stores e in sc[], denom in den[]
__global__ void attn_sc_k(const int* __restrict__ csrc, const unsigned* __restrict__ cptr,
                          const float* __restrict__ q1, const float* __restrict__ q2,
                          const float* __restrict__ attb, float* __restrict__ sc,
                          float* __restrict__ den) {
  int i = blockIdx.x * blockDim.x + threadIdx.x;
  if (i >= N_) return;
  unsigned p0 = cptr[i], p1 = cptr[i + 1];
  float base = q1[i] + attb[0];
  float m = -INFINITY;
  for (unsigned p = p0; p < p1; ++p) {
    float s = base + q2[csrc[p]];
    s = (s > 0.0f) ? s : 0.2f * s;
    sc[p] = s;
    m = fmaxf(m, s);
  }
  float d = 0.0f;
  for (unsigned p = p0; p < p1; ++p) {
    float e = expf(sc[p] - m);
    sc[p] = e;
    d += e;
  }
  den[i] = d;
}

__global__ void fitness_k(const unsigned* __restrict__ cptr, const int* __restrict__ csrc,
                          const float* __restrict__ av, const float* __restrict__ bv,
                          const float* __restrict__ c3, float* __restrict__ fit) {
  int i = blockIdx.x * blockDim.x + threadIdx.x;
  if (i >= N_) return;
  unsigned p0 = cptr[i], p1 = cptr[i + 1];
  float s = 0.0f;
  for (unsigned p = p0; p < p1; ++p) s += av[csrc[p]];
  float deg = (float)(p1 - p0);
  float val = s - deg * bv[i] + c3[i];
  fit[i] = 1.0f / (1.0f + expf(-val));
}

// ---------------------------------------------------------------------------
// Single-block exact top-K, fully parallel scans.
// 4x8-bit radix select on float bits (fit>0 so bit order == value order),
// exact smallest-index tie-break, bitonic sort of 256 winners.
// ---------------------------------------------------------------------------
__global__ __launch_bounds__(1024) void topk_k(const float* __restrict__ fit,
                                               unsigned* __restrict__ perm_i,
                                               float* __restrict__ fit_s,
                                               float* __restrict__ out_perm) {
  __shared__ unsigned hist[256 * 16];
  __shared__ unsigned scan_[256];
  __shared__ unsigned long long keys[K_];
  __shared__ unsigned s_pfx, s_rem, s_cnt, s_bstar, s_rem2, s_cut, s_all;
  int t = threadIdx.x;
  int sub = t & 15;

  unsigned msk = 0, pfx = 0, rem = K_;
  for (int lvl = 0; lvl < 4; ++lvl) {
    int shift = 24 - lvl * 8;
    for (int i = t; i < 256 * 16; i += 1024) hist[i] = 0;
    __syncthreads();
    for (int i = t; i < N_; i += 1024) {
      unsigned fb = __float_as_uint(fit[i]);
      if ((fb & msk) == pfx)
        atomicAdd(&hist[(((fb >> shift) & 0xFF) << 4) + sub], 1u);
    }
    __syncthreads();
    unsigned h = 0;
    if (t < 256) {
      for (int s = 0; s < 16; ++s) h += hist[(t << 4) + s];
      scan_[t] = h;
    }
    __syncthreads();
    // parallel suffix scan (descending select)
    for (int off = 1; off < 256; off <<= 1) {
      unsigned v = 0;
      if (t < 256 && t + off < 256) v = scan_[t + off];
      __syncthreads();
      if (t < 256) scan_[t] += v;
      __syncthreads();
    }
    if (t < 256) {
      unsigned suf = scan_[t];
      unsigned sufn = (t < 255) ? scan_[t + 1] : 0u;
      if (suf >= rem && sufn < rem) {
        s_pfx = pfx | ((unsigned)t << shift);
        s_rem = rem - sufn;
      }
    }
    __syncthreads();
    pfx = s_pfx; rem = s_rem; msk |= (0xFFu << shift);
    __syncthreads();
  }
  // pfx = exact bits of K-th largest; rem = #ties to take (smallest indices).
  if (t == 0) { s_cnt = 0; s_all = 0; }
  for (int i = t; i < 256 * 16; i += 1024) hist[i] = 0;
  __syncthreads();
  // fused: emit strict winners + histogram ties by idx>>7
  for (int i = t; i < N_; i += 1024) {
    unsigned fb = __float_as_uint(fit[i]);
    if (fb > pfx) {
      unsigned j = atomicAdd(&s_cnt, 1u);
      keys[j] = ((unsigned long long)fb << 32) | (unsigned long long)(0xFFFFFFFFu - (unsigned)i);
    } else if (fb == pfx) {
      atomicAdd(&hist[((i >> 7) << 4) + sub], 1u);
    }
  }
  __syncthreads();
  {
    unsigned h = 0;
    if (t < 256) {
      for (int s = 0; s < 16; ++s) h += hist[(t << 4) + s];
      scan_[t] = h;
    }
    __syncthreads();
    // ascending prefix scan
    for (int off = 1; off < 256; off <<= 1) {
      unsigned v = 0;
      if (t < 256 && t >= off) v = scan_[t - off];
      __syncthreads();
      if (t < 256) scan_[t] += v;
      __syncthreads();
    }
    if (t < 256) {
      unsigned pre = scan_[t];
      unsigned prev = (t > 0) ? scan_[t - 1] : 0u;
      if (t == 255 && pre == rem) s_all = 1u;           // all ties taken
      if (pre >= rem && prev < rem) { s_bstar = (unsigned)t; s_rem2 = rem - prev; }
    }
    __syncthreads();
  }
  unsigned bstar = s_bstar, rem2 = s_rem2;
  if (s_all) {
    for (int i = t; i < N_; i += 1024)
      if (__float_as_uint(fit[i]) == pfx) {
        unsigned j = atomicAdd(&s_cnt, 1u);
        keys[j] = ((unsigned long long)pfx << 32) | (unsigned long long)(0xFFFFFFFFu - (unsigned)i);
      }
  } else {
    for (int i = t; i < 256 * 16; i += 1024) hist[i] = 0;
    __syncthreads();
    for (int i = t; i < N_; i += 1024)
      if (__float_as_uint(fit[i]) == pfx && (unsigned)(i >> 7) == bstar)
        atomicAdd(&hist[((i & 127) << 4) + sub], 1u);
    __syncthreads();
    unsigned h = 0;
    if (t < 128) {
      for (int s = 0; s < 16; ++s) h += hist[(t << 4) + s];
      scan_[t] = h;
    }
    __syncthreads();
    for (int off = 1; off < 128; off <<= 1) {
      unsigned v = 0;
      if (t < 128 && t >= off) v = scan_[t - off];
      __syncthreads();
      if (t < 128) scan_[t] += v;
      __syncthreads();
    }
    if (t < 128) {
      unsigned pre = scan_[t];
      unsigned prev = (t > 0) ? scan_[t - 1] : 0u;
      if (pre >= rem2 && prev < rem2) s_cut = (unsigned)t;
    }
    __syncthreads();
    unsigned cut = s_cut;
    for (int i = t; i < N_; i += 1024) {
      if (__float_as_uint(fit[i]) == pfx) {
        unsigned hi = (unsigned)(i >> 7), lo = (unsigned)(i & 127);
        if (hi < bstar || (hi == bstar && lo <= cut)) {
          unsigned j = atomicAdd(&s_cnt, 1u);
          keys[j] = ((unsigned long long)pfx << 32) | (unsigned long long)(0xFFFFFFFFu - (unsigned)i);
        }
      }
    }
  }
  __syncthreads();
  // bitonic sort 256 keys descending -> (fit desc, idx asc)
  for (unsigned k = 2; k <= (unsigned)K_; k <<= 1) {
    for (unsigned j = k >> 1; j > 0; j >>= 1) {
      unsigned long long nv = 0;
      if (t < K_) {
        unsigned partner = (unsigned)t ^ j;
        unsigned long long a = keys[t], b = keys[partner];
        bool desc = ((t & k) == 0);
        bool tFirst = ((unsigned)t < partner);
        unsigned long long mx = (a > b) ? a : b;
        unsigned long long mn = (a > b) ? b : a;
        nv = (desc == tFirst) ? mx : mn;
      }
      __syncthreads();
      if (t < K_) keys[t] = nv;
      __syncthreads();
    }
  }
  if (t < K_) {
    unsigned long long kk = keys[t];
    unsigned idx = 0xFFFFFFFFu - (unsigned)(kk & 0xFFFFFFFFu);
    perm_i[t] = idx;
    fit_s[t] = __uint_as_float((unsigned)(kk >> 32));
    out_perm[t] = (float)idx;
  }
}

__global__ void xnew_k(const float* __restrict__ XC, const unsigned* __restrict__ perm_i,
                       const float* __restrict__ fit_s, float* __restrict__ out) {
  int g = blockIdx.x * blockDim.x + threadIdx.x;
  if (g >= K_ * F_) return;
  int k = g >> 6, f = g & 63;
  out[g] = XC[(size_t)perm_i[k] * F_ + f] * fit_s[k];
}

// build S triplets directly from the 256 selected nodes' CSR ranges
__global__ void trip_sel_k(const unsigned* __restrict__ perm_i, const unsigned* __restrict__ cptr,
                           const int* __restrict__ csrc, const float* __restrict__ sc,
                           const float* __restrict__ den,
                           int* __restrict__ ti, int* __restrict__ tk, float* __restrict__ tv,
                           unsigned* __restrict__ tcnt, unsigned* __restrict__ ctrl) {
  int k = blockIdx.x * blockDim.x + threadIdx.x;
  if (k >= K_) return;
  unsigned i = perm_i[k];
  unsigned p0 = cptr[i], p1 = cptr[i + 1];
  float d = den[i];
  for (unsigned p = p0; p < p1; ++p) {
    unsigned j = atomicAdd(&ctrl[5], 1u);
    if (j < (unsigned)TCAP) {
      int r = csrc[p];
      ti[j] = r; tk[j] = k; tv[j] = sc[p] / d;
      atomicAdd(&tcnt[r], 1u);
    }
  }
}

__global__ void trip_scatter_k(const int* __restrict__ ti, const unsigned* __restrict__ tptr,
                               unsigned* __restrict__ tcur, unsigned* __restrict__ tidx,
                               const unsigned* __restrict__ ctrl) {
  int g = blockIdx.x * blockDim.x + threadIdx.x;
  unsigned cnt = ctrl[5]; if (cnt > (unsigned)TCAP) cnt = TCAP;
  if (g >= (int)cnt) return;
  int i = ti[g];
  unsigned pos = tptr[i] + atomicAdd(&tcur[i], 1u);
  tidx[pos] = (unsigned)g;
}

// A[k1,k2] += sum over edges of S[row,k1]*S[col,k2]  (triplet pair expansion)
__global__ void anew_k(const int* __restrict__ rr, const int* __restrict__ cc,
                       const unsigned* __restrict__ tptr, const unsigned* __restrict__ tidx,
                       const int* __restrict__ tk, const float* __restrict__ tv,
                       float* __restrict__ A) {
  int g = blockIdx.x * blockDim.x + threadIdx.x;
  if (g >= M_) return;
  int i = rr[g], j = cc[g];
  unsigned a0 = tptr[i], a1 = tptr[i + 1];
  if (a0 == a1) return;
  unsigned b0 = tptr[j], b1 = tptr[j + 1];
  if (b0 == b1) return;
  for (unsigned pa = a0; pa < a1; ++pa) {
    unsigned ta = tidx[pa];
    int k1 = tk[ta];
    float va = tv[ta];
    float* Arow = A + (size_t)k1 * K_;
    for (unsigned pb = b0; pb < b1; ++pb) {
      unsigned tb = tidx[pb];
      atomicAdd(&Arow[tk[tb]], va * tv[tb]);
    }
  }
}

__global__ void adiag_k(float* __restrict__ A) {
  int t = threadIdx.x;
  if (t < K_) A[(size_t)t * K_ + t] = 1.0f;
}

// ---------------------------------------------------------------------------
extern "C" void kernel_launch(void* const* d_in, const int* in_sizes, int n_in,
                              void* d_out, int out_size, void* d_ws, size_t ws_size,
                              hipStream_t stream) {
  const float* x     = (const float*)d_in[0];
  const int*   ei    = (const int*)d_in[1];
  const float* W0    = (const float*)d_in[2];
  const float* b0    = (const float*)d_in[3];
  const float* W1    = (const float*)d_in[4];
  const float* b1    = (const float*)d_in[5];
  const float* linW  = (const float*)d_in[6];
  const float* linb  = (const float*)d_in[7];
  const float* attW  = (const float*)d_in[8];
  const float* attb  = (const float*)d_in[9];
  const float* le1W  = (const float*)d_in[10];
  const float* le1b  = (const float*)d_in[11];
  const float* le2W  = (const float*)d_in[12];
  const float* le3W  = (const float*)d_in[13];
  const float* le3b  = (const float*)d_in[14];

  float*    wf = (float*)d_ws;
  unsigned* wu = (unsigned*)d_ws;
  int*      wi = (int*)d_ws;
  float*    out = (float*)d_out;

  int*      rr    = wi + O_RR;
  int*      cc    = wi + O_CC;
  int*      csrc  = wi + O_CSRC;
  float*    cnrm  = wf + O_CNRM;
  float*    sc    = wf + O_SC;
  float*    bufA  = wf + O_BUFA;
  float*    bufB  = wf + O_BUFB;
  float*    bufC  = wf + O_BUFC;
  unsigned* cptr  = wu + O_CPTR;
  float*    q1    = wf + O_Q1;
  float*    q2    = wf + O_Q2;
  float*    den   = wf + O_DEN;
  float*    av    = wf + O_AV;
  float*    bv    = wf + O_BV;
  float*    c3    = wf + O_C3;
  float*    fit   = wf + O_FIT;
  unsigned* tptr  = wu + O_TPTR;
  int*      ti    = wi + O_TI;
  int*      tk    = wi + O_TK;
  float*    tv    = wf + O_TV;
  unsigned* tidx  = wu + O_TIDX;
  unsigned* perm_i= wu + O_PERM;
  float*    fit_s = wf + O_FITS;
  float*    wq    = wf + O_WQ;
  unsigned* zr    = wu + O_ZR;
  unsigned* cnt   = wu + O_CNT;
  unsigned* cur   = wu + O_CUR;
  unsigned* tcnt  = wu + O_TCNT;
  unsigned* tcur  = wu + O_TCUR;
  unsigned* ctrl  = wu + O_CTRL;

  const int TB = 256;
  const int gM = (M_ + TB - 1) / TB;          // 1329
  const int gN = (N_ + TB - 1) / TB;          // 79
  const int gW = (N_ + 3) / 4;                // 5000 (wave-per-node, 4 waves/block)
  const int gG = (N_ + 63) / 64;              // 313 (gemm tiles)
  const int gZ = ((int)(ZR_WORDS > OUT_WORDS ? ZR_WORDS : OUT_WORDS) + TB - 1) / TB;

  hipLaunchKernelGGL(init_k, dim3(gZ), dim3(TB), 0, stream, zr, out);
  hipLaunchKernelGGL(build_edges_k, dim3(gM), dim3(TB), 0, stream, ei, rr, cc, cnt);
  hipLaunchKernelGGL(prefix_k, dim3(1), dim3(1024), 0, stream, cnt, cptr, N_);
  hipLaunchKernelGGL(scatter_csr_k, dim3(gM), dim3(TB), 0, stream, rr, cc, cptr, cur, csrc, cnrm);
  hipLaunchKernelGGL(wq_k, dim3(1), dim3(64), 0, stream, linW, linb, attW, wq);

  // GCN layer 1: bufA = x@W0 ; bufB = relu(agg + b0)
  hipLaunchKernelGGL(gemm64_k, dim3(gG), dim3(TB), 0, stream, x, W0, bufA);
  hipLaunchKernelGGL((agg_k<0, 0, true, false>), dim3(gW), dim3(TB), 0, stream, bufA, csrc, cnrm, cptr, b0, bufB,
                     nullptr, nullptr, nullptr, nullptr, nullptr, nullptr, nullptr, nullptr, nullptr, nullptr, nullptr);
  // GCN layer 2: bufA = bufB@W1 ; bufC = relu(agg + b1) = x2 ; q2 epilogue
  hipLaunchKernelGGL(gemm64_k, dim3(gG), dim3(TB), 0, stream, bufB, W1, bufA);
  hipLaunchKernelGGL((agg_k<0, 1, true, false>), dim3(gW), dim3(TB), 0, stream, bufA, csrc, cnrm, cptr, b1, bufC,
                     attW, q2, nullptr, nullptr, nullptr, nullptr, nullptr, nullptr, nullptr, nullptr, nullptr);

  // attention pooling: segment_max with folded lin·att epilogue -> scores -> xc
  hipLaunchKernelGGL((agg_k<1, 3, false, false>), dim3(gW), dim3(TB), 0, stream, bufC, csrc,
                     (const float*)nullptr, cptr, (const float*)nullptr, nullptr,
                     wq, q1, nullptr, nullptr, nullptr, nullptr, nullptr, nullptr, nullptr, nullptr, nullptr);
  hipLaunchKernelGGL(attn_sc_k, dim3(gN), dim3(TB), 0, stream, csrc, cptr, q1, q2, attb, sc, den);
  hipLaunchKernelGGL((agg_k<2, 2, true, true>), dim3(gW), dim3(TB), 0, stream, bufC, csrc, sc, cptr,
                     (const float*)nullptr, bufB, nullptr, nullptr, le1W, le1b, le2W, le3W, le3b, av, bv, c3, den);

  // fitness + exact top-K
  hipLaunchKernelGGL(fitness_k, dim3(gN), dim3(TB), 0, stream, cptr, csrc, av, bv, c3, fit);
  hipLaunchKernelGGL(topk_k, dim3(1), dim3(1024), 0, stream, fit, perm_i, fit_s, out + K_ * F_ + K_ * K_);
  hipLaunchKernelGGL(xnew_k, dim3((K_ * F_) / TB), dim3(TB), 0, stream, bufB, perm_i, fit_s, out);

  // sparse S triplets -> A_new
  hipLaunchKernelGGL(trip_sel_k, dim3(1), dim3(TB), 0, stream, perm_i, cptr, csrc, sc, den, ti, tk, tv, tcnt, ctrl);
  hipLaunchKernelGGL(prefix_k, dim3(1), dim3(1024), 0, stream, tcnt, tptr, N_);
  hipLaunchKernelGGL(trip_scatter_k, dim3(TCAP / TB), dim3(TB), 0, stream, ti, tptr, tcur, tidx, ctrl);
  hipLaunchKernelGGL(anew_k, dim3(gM), dim3(TB), 0, stream, rr, cc, tptr, tidx, tk, tv, out + K_ * F_);
  hipLaunchKernelGGL(adiag_k, dim3(1), dim3(TB), 0, stream, out + K_ * F_);

  (void)in_sizes; (void)n_in; (void)out_size; (void)ws_size;
}

// Round 6
// 356.578 us; speedup vs baseline: 1.9654x; 1.2598x over previous
//
#include <hip/hip_runtime.h>
#include <math.h>

// ---------------------------------------------------------------------------
// ASAP pooling block, fixed shapes.
// ---------------------------------------------------------------------------
constexpr int N_ = 20000;
constexpr int E_ = 320000;
constexpr int M_ = E_ + N_;      // edges incl. self loops
constexpr int F_ = 64;
constexpr int K_ = 256;
constexpr int TCAP = 32768;      // S-triplet capacity (expected ~4400)
constexpr int OUT_WORDS = K_ * F_ + K_ * K_ + K_;   // 82176

// ---- workspace layout (word offsets; 16B-aligned where float4-read) -------
constexpr size_t O_RR   = 0;
constexpr size_t O_CC   = O_RR + M_;
constexpr size_t O_CSRC = O_CC + M_;                   // CSR(by col) source node
constexpr size_t O_CNRM = O_CSRC + M_;                 // CSR gcn norm weight
constexpr size_t O_SC   = O_CNRM + M_;                 // CSR attention exp(score)
constexpr size_t O_BUFA = O_SC + M_;
constexpr size_t O_BUFB = O_BUFA + (size_t)N_ * F_;
constexpr size_t O_BUFC = O_BUFB + (size_t)N_ * F_;
constexpr size_t O_CPTR = O_BUFC + (size_t)N_ * F_;    // N+1 (padded to N+4)
constexpr size_t O_Q2   = O_CPTR + N_ + 4;
constexpr size_t O_DEN  = O_Q2 + N_;
constexpr size_t O_AV   = O_DEN + N_;
constexpr size_t O_BV   = O_AV + N_;
constexpr size_t O_C3   = O_BV + N_;
constexpr size_t O_FIT  = O_C3 + N_;
constexpr size_t O_TPTR = O_FIT + N_;                  // N+1 (padded to N+4)
constexpr size_t O_TI   = O_TPTR + N_ + 4;
constexpr size_t O_TK   = O_TI + TCAP;
constexpr size_t O_TV   = O_TK + TCAP;
constexpr size_t O_TIDX = O_TV + TCAP;
constexpr size_t O_PERM = O_TIDX + TCAP;               // 256 (uint)
constexpr size_t O_FITS = O_PERM + K_;                 // 256 (f32)
constexpr size_t O_WQ   = O_FITS + K_;                 // 65 (lin/att folded vec + bias)
// zero-initialized region:
constexpr size_t O_ZR   = O_WQ + 72;
constexpr size_t O_CNT  = O_ZR;                        // N (in-degree counts)
constexpr size_t O_CUR  = O_CNT + N_;                  // N
constexpr size_t O_TCNT = O_CUR + N_;                  // N
constexpr size_t O_TCUR = O_TCNT + N_;                 // N
constexpr size_t O_CTRL = O_TCUR + N_;                 // 8 (ctrl[5]=trip count)
constexpr size_t ZR_WORDS = O_CTRL + 8 - O_ZR;

__device__ __forceinline__ float4 ld4(const float* p) { return *reinterpret_cast<const float4*>(p); }
__device__ __forceinline__ void st4(float* p, float4 v) { *reinterpret_cast<float4*>(p) = v; }

// ---------------------------------------------------------------------------
__global__ void init_k(unsigned* __restrict__ zr, float* __restrict__ dout) {
  int g = blockIdx.x * blockDim.x + threadIdx.x;
  if (g < (int)ZR_WORDS) zr[g] = 0u;
  if (g < OUT_WORDS) dout[g] = 0.0f;
}

// edges + degree counts; last block also computes wq = linW@attW[:64], wq[64]=linb·attW
__global__ void build_edges_k(const int* __restrict__ ei, int* __restrict__ rr,
                              int* __restrict__ cc, unsigned* __restrict__ cnt,
                              const float* __restrict__ linW, const float* __restrict__ linb,
                              const float* __restrict__ attW, float* __restrict__ wq) {
  if (blockIdx.x == gridDim.x - 1) {
    int f = threadIdx.x;
    if (f < 64) {
      float s = 0.0f;
      for (int c = 0; c < 64; ++c) s += linW[f * 64 + c] * attW[c];
      wq[f] = s;
      float b = linb[f] * attW[f];
      for (int off = 32; off; off >>= 1) b += __shfl_down(b, off);
      if (f == 0) wq[64] = b;
    }
    return;
  }
  int g = blockIdx.x * blockDim.x + threadIdx.x;
  if (g >= M_) return;
  int r, c;
  if (g < E_) { r = ei[g]; c = ei[E_ + g]; } else { r = g - E_; c = r; }
  rr[g] = r; cc[g] = c;
  atomicAdd(&cnt[c], 1u);
}

// single-block exclusive prefix (n bins -> ptr[n+1])
__global__ void prefix_k(const unsigned* __restrict__ cnt, unsigned* __restrict__ ptr, int n) {
  __shared__ unsigned part[1024];
  int t = threadIdx.x;
  int chunk = (n + 1023) >> 10;
  int i0 = t * chunk;
  unsigned s = 0;
  for (int j = 0; j < chunk; ++j) { int i = i0 + j; if (i < n) s += cnt[i]; }
  part[t] = s; __syncthreads();
  for (int off = 1; off < 1024; off <<= 1) {
    unsigned v = (t >= off) ? part[t - off] : 0u;
    __syncthreads();
    part[t] += v;
    __syncthreads();
  }
  unsigned run = part[t] - s;
  for (int j = 0; j < chunk; ++j) {
    int i = i0 + j;
    if (i < n) { ptr[i] = run; run += cnt[i]; }
  }
  if (t == 0) ptr[n] = part[1023];
}

// scatter edge -> CSR(by col) position; store src node and gcn norm weight
__global__ void scatter_csr_k(const int* __restrict__ rr, const int* __restrict__ cc,
                              const unsigned* __restrict__ cptr, unsigned* __restrict__ cur,
                              int* __restrict__ csrc, float* __restrict__ cnrm) {
  int g = blockIdx.x * blockDim.x + threadIdx.x;
  if (g >= M_) return;
  int r = rr[g], c = cc[g];
  unsigned pos = cptr[c] + atomicAdd(&cur[c], 1u);
  csrc[pos] = r;
  float dr = (float)(cptr[r + 1] - cptr[r]);
  float dc = (float)(cptr[c + 1] - cptr[c]);
  cnrm[pos] = (1.0f / sqrtf(dr)) * (1.0f / sqrtf(dc));
}

// Y[n,64] = X[n,64] @ W[64,64]. Tiled: 64 rows/block, 256 threads.
__global__ void gemm64_k(const float* __restrict__ X, const float* __restrict__ W,
                         float* __restrict__ Y) {
  __shared__ float xs[64][64];
  __shared__ float wsh[64][64];
  int t = threadIdx.x;
  int r0 = blockIdx.x * 64;
  for (int i = 0; i < 16; ++i) {
    int idx = t + i * 256;
    wsh[idx >> 6][idx & 63] = W[idx];
  }
  for (int i = 0; i < 16; ++i) {
    int idx = t + i * 256;
    int r = idx >> 6, c = idx & 63;
    xs[r][c] = (r0 + r < N_) ? X[(size_t)(r0 + r) * F_ + c] : 0.0f;
  }
  __syncthreads();
  int c = t & 63, rg = t >> 6;
  float acc[16];
#pragma unroll
  for (int m = 0; m < 16; ++m) acc[m] = 0.0f;
  for (int k = 0; k < 64; ++k) {
    float w = wsh[k][c];
#pragma unroll
    for (int m = 0; m < 16; ++m) acc[m] += xs[rg + 4 * m][k] * w;
  }
  for (int m = 0; m < 16; ++m) {
    int r = r0 + rg + 4 * m;
    if (r < N_) Y[(size_t)r * F_ + c] = acc[m];
  }
}

// GCN aggregate, vectorized: wave per node; 16 lanes x float4 per row, 4 edges
// in flight. EPI 1: q2[i] = relu_out · attW[64:128].
template<int EPI>
__global__ void agg_gcn_k(const float* __restrict__ H, const int* __restrict__ csrc,
                          const float* __restrict__ wts, const unsigned* __restrict__ cptr,
                          const float* __restrict__ bias, float* __restrict__ Y,
                          const float* __restrict__ attW, float* __restrict__ q2) {
  int wid = blockIdx.x * (blockDim.x >> 6) + (threadIdx.x >> 6);
  int lane = threadIdx.x & 63;
  if (wid >= N_) return;
  int sub = lane >> 4, fq = lane & 15;
  unsigned p0 = cptr[wid], p1 = cptr[wid + 1];
  float ax = 0.f, ay = 0.f, az = 0.f, aw = 0.f;
  for (unsigned p = p0 + sub; p < p1; p += 4) {
    int s = csrc[p];
    float w = wts[p];
    float4 h = ld4(H + (size_t)s * F_ + 4 * fq);
    ax += w * h.x; ay += w * h.y; az += w * h.z; aw += w * h.w;
  }
#pragma unroll
  for (int off = 16; off <= 32; off <<= 1) {
    ax += __shfl_xor(ax, off); ay += __shfl_xor(ay, off);
    az += __shfl_xor(az, off); aw += __shfl_xor(aw, off);
  }
  float4 b4 = ld4(bias + 4 * fq);
  ax = fmaxf(ax + b4.x, 0.f); ay = fmaxf(ay + b4.y, 0.f);
  az = fmaxf(az + b4.z, 0.f); aw = fmaxf(aw + b4.w, 0.f);
  if (sub == 0) { float4 o{ax, ay, az, aw}; st4(Y + (size_t)wid * F_ + 4 * fq, o); }
  if (EPI == 1) {
    float4 a4 = ld4(attW + 64 + 4 * fq);
    float v = ax * a4.x + ay * a4.y + az * a4.z + aw * a4.w;
#pragma unroll
    for (int off = 1; off <= 8; off <<= 1) v += __shfl_xor(v, off);
    if (lane == 0) q2[wid] = v;
  }
}

// Fused attention: segment-max (+folded lin·att -> q1) -> leaky/softmax stats
// -> xc weighted gather (+le1/le2/le3 dots). Wave per node.
__global__ void attn_fused_k(const float* __restrict__ X2, const int* __restrict__ csrc,
                             const unsigned* __restrict__ cptr, const float* __restrict__ q2,
                             const float* __restrict__ attb, const float* __restrict__ wq,
                             float* __restrict__ sc, float* __restrict__ den,
                             float* __restrict__ XC,
                             const float* __restrict__ le1W, const float* __restrict__ le1b,
                             const float* __restrict__ le2W, const float* __restrict__ le3W,
                             const float* __restrict__ le3b, float* __restrict__ av,
                             float* __restrict__ bv, float* __restrict__ c3) {
  int wid = blockIdx.x * (blockDim.x >> 6) + (threadIdx.x >> 6);
  int lane = threadIdx.x & 63;
  if (wid >= N_) return;
  int sub = lane >> 4, fq = lane & 15;
  unsigned p0 = cptr[wid], p1 = cptr[wid + 1];
  // phase A: feature-wise segment max + q1 dot
  float mx = -INFINITY, my = -INFINITY, mz = -INFINITY, mw = -INFINITY;
  for (unsigned p = p0 + sub; p < p1; p += 4) {
    int s = csrc[p];
    float4 h = ld4(X2 + (size_t)s * F_ + 4 * fq);
    mx = fmaxf(mx, h.x); my = fmaxf(my, h.y); mz = fmaxf(mz, h.z); mw = fmaxf(mw, h.w);
  }
#pragma unroll
  for (int off = 16; off <= 32; off <<= 1) {
    mx = fmaxf(mx, __shfl_xor(mx, off)); my = fmaxf(my, __shfl_xor(my, off));
    mz = fmaxf(mz, __shfl_xor(mz, off)); mw = fmaxf(mw, __shfl_xor(mw, off));
  }
  float4 w4 = ld4(wq + 4 * fq);
  float q1v = mx * w4.x + my * w4.y + mz * w4.z + mw * w4.w;
#pragma unroll
  for (int off = 1; off <= 8; off <<= 1) q1v += __shfl_xor(q1v, off);
  float base = q1v + wq[64] + attb[0];
  // phase B: leaky score max, exp-sum; lanes split edges
  float m = -INFINITY;
  for (unsigned p = p0 + lane; p < p1; p += 64) {
    float s = base + q2[csrc[p]];
    s = (s > 0.0f) ? s : 0.2f * s;
    m = fmaxf(m, s);
  }
#pragma unroll
  for (int off = 1; off <= 32; off <<= 1) m = fmaxf(m, __shfl_xor(m, off));
  float d = 0.0f;
  for (unsigned p = p0 + lane; p < p1; p += 64) {
    float s = base + q2[csrc[p]];
    s = (s > 0.0f) ? s : 0.2f * s;
    float e = expf(s - m);
    sc[p] = e;
    d += e;
  }
#pragma unroll
  for (int off = 1; off <= 32; off <<= 1) d += __shfl_xor(d, off);
  if (lane == 0) den[wid] = d;
  // phase C: xc = (sum e*x)/d ; recompute e (bit-identical) to avoid x-lane mem
  float ax = 0.f, ay = 0.f, az = 0.f, aw = 0.f;
  for (unsigned p = p0 + sub; p < p1; p += 4) {
    int s = csrc[p];
    float sv = base + q2[s];
    sv = (sv > 0.0f) ? sv : 0.2f * sv;
    float w = expf(sv - m);
    float4 h = ld4(X2 + (size_t)s * F_ + 4 * fq);
    ax += w * h.x; ay += w * h.y; az += w * h.z; aw += w * h.w;
  }
#pragma unroll
  for (int off = 16; off <= 32; off <<= 1) {
    ax += __shfl_xor(ax, off); ay += __shfl_xor(ay, off);
    az += __shfl_xor(az, off); aw += __shfl_xor(aw, off);
  }
  float inv = 1.0f / d;
  ax *= inv; ay *= inv; az *= inv; aw *= inv;
  if (sub == 0) { float4 o{ax, ay, az, aw}; st4(XC + (size_t)wid * F_ + 4 * fq, o); }
  float4 l1 = ld4(le1W + 4 * fq), l2 = ld4(le2W + 4 * fq), l3 = ld4(le3W + 4 * fq);
  float s1 = ax * l1.x + ay * l1.y + az * l1.z + aw * l1.w;
  float s2 = ax * l2.x + ay * l2.y + az * l2.z + aw * l2.w;
  float s3 = ax * l3.x + ay * l3.y + az * l3.z + aw * l3.w;
#pragma unroll
  for (int off = 1; off <= 8; off <<= 1) {
    s1 += __shfl_xor(s1, off); s2 += __shfl_xor(s2, off); s3 += __shfl_xor(s3, off);
  }
  if (lane == 0) { av[wid] = s1 + le1b[0]; bv[wid] = s2; c3[wid] = s3 + le3b[0]; }
}

// fitness: wave per node, lanes split edges
__global__ void fitness_k(const unsigned* __restrict__ cptr, const int* __restrict__ csrc,
                          const float* __restrict__ av, const float* __restrict__ bv,
                          const float* __restrict__ c3, float* __restrict__ fit) {
  int wid = blockIdx.x * (blockDim.x >> 6) + (threadIdx.x >> 6);
  int lane = threadIdx.x & 63;
  if (wid >= N_) return;
  unsigned p0 = cptr[wid], p1 = cptr[wid + 1];
  float s = 0.0f;
  for (unsigned p = p0 + lane; p < p1; p += 64) s += av[csrc[p]];
#pragma unroll
  for (int off = 1; off <= 32; off <<= 1) s += __shfl_xor(s, off);
  if (lane == 0) {
    float deg = (float)(p1 - p0);
    float val = s - deg * bv[wid] + c3[wid];
    fit[wid] = 1.0f / (1.0f + expf(-val));
  }
}

// ---------------------------------------------------------------------------
// Single-block exact top-K, fully parallel scans.
// ---------------------------------------------------------------------------
__global__ __launch_bounds__(1024) void topk_k(const float* __restrict__ fit,
                                               unsigned* __restrict__ perm_i,
                                               float* __restrict__ fit_s,
                                               float* __restrict__ out_perm) {
  __shared__ unsigned hist[256 * 16];
  __shared__ unsigned scan_[256];
  __shared__ unsigned long long keys[K_];
  __shared__ unsigned s_pfx, s_rem, s_cnt, s_bstar, s_rem2, s_cut, s_all;
  int t = threadIdx.x;
  int sub = t & 15;

  unsigned msk = 0, pfx = 0, rem = K_;
  for (int lvl = 0; lvl < 4; ++lvl) {
    int shift = 24 - lvl * 8;
    for (int i = t; i < 256 * 16; i += 1024) hist[i] = 0;
    __syncthreads();
    for (int i = t; i < N_; i += 1024) {
      unsigned fb = __float_as_uint(fit[i]);
      if ((fb & msk) == pfx)
        atomicAdd(&hist[(((fb >> shift) & 0xFF) << 4) + sub], 1u);
    }
    __syncthreads();
    unsigned h = 0;
    if (t < 256) {
      for (int s = 0; s < 16; ++s) h += hist[(t << 4) + s];
      scan_[t] = h;
    }
    __syncthreads();
    for (int off = 1; off < 256; off <<= 1) {
      unsigned v = 0;
      if (t < 256 && t + off < 256) v = scan_[t + off];
      __syncthreads();
      if (t < 256) scan_[t] += v;
      __syncthreads();
    }
    if (t < 256) {
      unsigned suf = scan_[t];
      unsigned sufn = (t < 255) ? scan_[t + 1] : 0u;
      if (suf >= rem && sufn < rem) {
        s_pfx = pfx | ((unsigned)t << shift);
        s_rem = rem - sufn;
      }
    }
    __syncthreads();
    pfx = s_pfx; rem = s_rem; msk |= (0xFFu << shift);
    __syncthreads();
  }
  if (t == 0) { s_cnt = 0; s_all = 0; }
  for (int i = t; i < 256 * 16; i += 1024) hist[i] = 0;
  __syncthreads();
  for (int i = t; i < N_; i += 1024) {
    unsigned fb = __float_as_uint(fit[i]);
    if (fb > pfx) {
      unsigned j = atomicAdd(&s_cnt, 1u);
      keys[j] = ((unsigned long long)fb << 32) | (unsigned long long)(0xFFFFFFFFu - (unsigned)i);
    } else if (fb == pfx) {
      atomicAdd(&hist[((i >> 7) << 4) + sub], 1u);
    }
  }
  __syncthreads();
  {
    unsigned h = 0;
    if (t < 256) {
      for (int s = 0; s < 16; ++s) h += hist[(t << 4) + s];
      scan_[t] = h;
    }
    __syncthreads();
    for (int off = 1; off < 256; off <<= 1) {
      unsigned v = 0;
      if (t < 256 && t >= off) v = scan_[t - off];
      __syncthreads();
      if (t < 256) scan_[t] += v;
      __syncthreads();
    }
    if (t < 256) {
      unsigned pre = scan_[t];
      unsigned prev = (t > 0) ? scan_[t - 1] : 0u;
      if (t == 255 && pre == rem) s_all = 1u;
      if (pre >= rem && prev < rem) { s_bstar = (unsigned)t; s_rem2 = rem - prev; }
    }
    __syncthreads();
  }
  unsigned bstar = s_bstar, rem2 = s_rem2;
  if (s_all) {
    for (int i = t; i < N_; i += 1024)
      if (__float_as_uint(fit[i]) == pfx) {
        unsigned j = atomicAdd(&s_cnt, 1u);
        keys[j] = ((unsigned long long)pfx << 32) | (unsigned long long)(0xFFFFFFFFu - (unsigned)i);
      }
  } else {
    for (int i = t; i < 256 * 16; i += 1024) hist[i] = 0;
    __syncthreads();
    for (int i = t; i < N_; i += 1024)
      if (__float_as_uint(fit[i]) == pfx && (unsigned)(i >> 7) == bstar)
        atomicAdd(&hist[((i & 127) << 4) + sub], 1u);
    __syncthreads();
    unsigned h = 0;
    if (t < 128) {
      for (int s = 0; s < 16; ++s) h += hist[(t << 4) + s];
      scan_[t] = h;
    }
    __syncthreads();
    for (int off = 1; off < 128; off <<= 1) {
      unsigned v = 0;
      if (t < 128 && t >= off) v = scan_[t - off];
      __syncthreads();
      if (t < 128) scan_[t] += v;
      __syncthreads();
    }
    if (t < 128) {
      unsigned pre = scan_[t];
      unsigned prev = (t > 0) ? scan_[t - 1] : 0u;
      if (pre >= rem2 && prev < rem2) s_cut = (unsigned)t;
    }
    __syncthreads();
    unsigned cut = s_cut;
    for (int i = t; i < N_; i += 1024) {
      if (__float_as_uint(fit[i]) == pfx) {
        unsigned hi = (unsigned)(i >> 7), lo = (unsigned)(i & 127);
        if (hi < bstar || (hi == bstar && lo <= cut)) {
          unsigned j = atomicAdd(&s_cnt, 1u);
          keys[j] = ((unsigned long long)pfx << 32) | (unsigned long long)(0xFFFFFFFFu - (unsigned)i);
        }
      }
    }
  }
  __syncthreads();
  for (unsigned k = 2; k <= (unsigned)K_; k <<= 1) {
    for (unsigned j = k >> 1; j > 0; j >>= 1) {
      unsigned long long nv = 0;
      if (t < K_) {
        unsigned partner = (unsigned)t ^ j;
        unsigned long long a = keys[t], b = keys[partner];
        bool desc = ((t & k) == 0);
        bool tFirst = ((unsigned)t < partner);
        unsigned long long mx2 = (a > b) ? a : b;
        unsigned long long mn = (a > b) ? b : a;
        nv = (desc == tFirst) ? mx2 : mn;
      }
      __syncthreads();
      if (t < K_) keys[t] = nv;
      __syncthreads();
    }
  }
  if (t < K_) {
    unsigned long long kk = keys[t];
    unsigned idx = 0xFFFFFFFFu - (unsigned)(kk & 0xFFFFFFFFu);
    perm_i[t] = idx;
    fit_s[t] = __uint_as_float((unsigned)(kk >> 32));
    out_perm[t] = (float)idx;
  }
}

__global__ void xnew_k(const float* __restrict__ XC, const unsigned* __restrict__ perm_i,
                       const float* __restrict__ fit_s, float* __restrict__ out) {
  int g = blockIdx.x * blockDim.x + threadIdx.x;
  if (g >= K_ * F_ / 4) return;
  int k = g >> 4, fq = g & 15;
  float4 v = ld4(XC + (size_t)perm_i[k] * F_ + 4 * fq);
  float f = fit_s[k];
  v.x *= f; v.y *= f; v.z *= f; v.w *= f;
  st4(out + (size_t)k * F_ + 4 * fq, v);
}

// build S triplets directly from the 256 selected nodes' CSR ranges
__global__ void trip_sel_k(const unsigned* __restrict__ perm_i, const unsigned* __restrict__ cptr,
                           const int* __restrict__ csrc, const float* __restrict__ sc,
                           const float* __restrict__ den,
                           int* __restrict__ ti, int* __restrict__ tk, float* __restrict__ tv,
                           unsigned* __restrict__ tcnt, unsigned* __restrict__ ctrl) {
  int k = blockIdx.x * blockDim.x + threadIdx.x;
  if (k >= K_) return;
  unsigned i = perm_i[k];
  unsigned p0 = cptr[i], p1 = cptr[i + 1];
  float d = den[i];
  for (unsigned p = p0; p < p1; ++p) {
    unsigned j = atomicAdd(&ctrl[5], 1u);
    if (j < (unsigned)TCAP) {
      int r = csrc[p];
      ti[j] = r; tk[j] = k; tv[j] = sc[p] / d;
      atomicAdd(&tcnt[r], 1u);
    }
  }
}

__global__ void trip_scatter_k(const int* __restrict__ ti, const unsigned* __restrict__ tptr,
                               unsigned* __restrict__ tcur, unsigned* __restrict__ tidx,
                               const unsigned* __restrict__ ctrl) {
  int g = blockIdx.x * blockDim.x + threadIdx.x;
  unsigned cnt = ctrl[5]; if (cnt > (unsigned)TCAP) cnt = TCAP;
  if (g >= (int)cnt) return;
  int i = ti[g];
  unsigned pos = tptr[i] + atomicAdd(&tcur[i], 1u);
  tidx[pos] = (unsigned)g;
}

// A[k1,k2] += sum over edges of S[row,k1]*S[col,k2]
__global__ void anew_k(const int* __restrict__ rr, const int* __restrict__ cc,
                       const unsigned* __restrict__ tptr, const unsigned* __restrict__ tidx,
                       const int* __restrict__ tk, const float* __restrict__ tv,
                       float* __restrict__ A) {
  int g = blockIdx.x * blockDim.x + threadIdx.x;
  if (g >= M_) return;
  int i = rr[g], j = cc[g];
  unsigned a0 = tptr[i], a1 = tptr[i + 1];
  if (a0 == a1) return;
  unsigned b0 = tptr[j], b1 = tptr[j + 1];
  if (b0 == b1) return;
  for (unsigned pa = a0; pa < a1; ++pa) {
    unsigned ta = tidx[pa];
    int k1 = tk[ta];
    float va = tv[ta];
    float* Arow = A + (size_t)k1 * K_;
    for (unsigned pb = b0; pb < b1; ++pb) {
      unsigned tb = tidx[pb];
      atomicAdd(&Arow[tk[tb]], va * tv[tb]);
    }
  }
}

__global__ void adiag_k(float* __restrict__ A) {
  int t = threadIdx.x;
  if (t < K_) A[(size_t)t * K_ + t] = 1.0f;
}

// ---------------------------------------------------------------------------
extern "C" void kernel_launch(void* const* d_in, const int* in_sizes, int n_in,
                              void* d_out, int out_size, void* d_ws, size_t ws_size,
                              hipStream_t stream) {
  const float* x     = (const float*)d_in[0];
  const int*   ei    = (const int*)d_in[1];
  const float* W0    = (const float*)d_in[2];
  const float* b0    = (const float*)d_in[3];
  const float* W1    = (const float*)d_in[4];
  const float* b1    = (const float*)d_in[5];
  const float* linW  = (const float*)d_in[6];
  const float* linb  = (const float*)d_in[7];
  const float* attW  = (const float*)d_in[8];
  const float* attb  = (const float*)d_in[9];
  const float* le1W  = (const float*)d_in[10];
  const float* le1b  = (const float*)d_in[11];
  const float* le2W  = (const float*)d_in[12];
  const float* le3W  = (const float*)d_in[13];
  const float* le3b  = (const float*)d_in[14];

  float*    wf = (float*)d_ws;
  unsigned* wu = (unsigned*)d_ws;
  int*      wi = (int*)d_ws;
  float*    out = (float*)d_out;

  int*      rr    = wi + O_RR;
  int*      cc    = wi + O_CC;
  int*      csrc  = wi + O_CSRC;
  float*    cnrm  = wf + O_CNRM;
  float*    sc    = wf + O_SC;
  float*    bufA  = wf + O_BUFA;
  float*    bufB  = wf + O_BUFB;
  float*    bufC  = wf + O_BUFC;
  unsigned* cptr  = wu + O_CPTR;
  float*    q2    = wf + O_Q2;
  float*    den   = wf + O_DEN;
  float*    av    = wf + O_AV;
  float*    bv    = wf + O_BV;
  float*    c3    = wf + O_C3;
  float*    fit   = wf + O_FIT;
  unsigned* tptr  = wu + O_TPTR;
  int*      ti    = wi + O_TI;
  int*      tk    = wi + O_TK;
  float*    tv    = wf + O_TV;
  unsigned* tidx  = wu + O_TIDX;
  unsigned* perm_i= wu + O_PERM;
  float*    fit_s = wf + O_FITS;
  float*    wq    = wf + O_WQ;
  unsigned* zr    = wu + O_ZR;
  unsigned* cnt   = wu + O_CNT;
  unsigned* cur   = wu + O_CUR;
  unsigned* tcnt  = wu + O_TCNT;
  unsigned* tcur  = wu + O_TCUR;
  unsigned* ctrl  = wu + O_CTRL;

  const int TB = 256;
  const int gM = (M_ + TB - 1) / TB;          // 1329
  const int gW = (N_ + 3) / 4;                // 5000 (wave-per-node, 4 waves/block)
  const int gG = (N_ + 63) / 64;              // 313 (gemm tiles)
  const int gZ = ((int)(ZR_WORDS > OUT_WORDS ? ZR_WORDS : OUT_WORDS) + TB - 1) / TB;

  hipLaunchKernelGGL(init_k, dim3(gZ), dim3(TB), 0, stream, zr, out);
  hipLaunchKernelGGL(build_edges_k, dim3(gM + 1), dim3(TB), 0, stream, ei, rr, cc, cnt,
                     linW, linb, attW, wq);
  hipLaunchKernelGGL(prefix_k, dim3(1), dim3(1024), 0, stream, cnt, cptr, N_);
  hipLaunchKernelGGL(scatter_csr_k, dim3(gM), dim3(TB), 0, stream, rr, cc, cptr, cur, csrc, cnrm);

  // GCN layer 1: bufA = x@W0 ; bufB = relu(agg + b0)
  hipLaunchKernelGGL(gemm64_k, dim3(gG), dim3(TB), 0, stream, x, W0, bufA);
  hipLaunchKernelGGL((agg_gcn_k<0>), dim3(gW), dim3(TB), 0, stream, bufA, csrc, cnrm, cptr, b0, bufB,
                     nullptr, nullptr);
  // GCN layer 2: bufA = bufB@W1 ; bufC = relu(agg + b1) = x2 ; q2 epilogue
  hipLaunchKernelGGL(gemm64_k, dim3(gG), dim3(TB), 0, stream, bufB, W1, bufA);
  hipLaunchKernelGGL((agg_gcn_k<1>), dim3(gW), dim3(TB), 0, stream, bufA, csrc, cnrm, cptr, b1, bufC,
                     attW, q2);

  // fused attention pooling (xc -> bufB) + le dots
  hipLaunchKernelGGL(attn_fused_k, dim3(gW), dim3(TB), 0, stream, bufC, csrc, cptr, q2, attb, wq,
                     sc, den, bufB, le1W, le1b, le2W, le3W, le3b, av, bv, c3);

  // fitness + exact top-K
  hipLaunchKernelGGL(fitness_k, dim3(gW), dim3(TB), 0, stream, cptr, csrc, av, bv, c3, fit);
  hipLaunchKernelGGL(topk_k, dim3(1), dim3(1024), 0, stream, fit, perm_i, fit_s, out + K_ * F_ + K_ * K_);
  hipLaunchKernelGGL(xnew_k, dim3((K_ * F_ / 4 + TB - 1) / TB), dim3(TB), 0, stream, bufB, perm_i, fit_s, out);

  // sparse S triplets -> A_new
  hipLaunchKernelGGL(trip_sel_k, dim3(1), dim3(TB), 0, stream, perm_i, cptr, csrc, sc, den, ti, tk, tv, tcnt, ctrl);
  hipLaunchKernelGGL(prefix_k, dim3(1), dim3(1024), 0, stream, tcnt, tptr, N_);
  hipLaunchKernelGGL(trip_scatter_k, dim3(TCAP / TB), dim3(TB), 0, stream, ti, tptr, tcur, tidx, ctrl);
  hipLaunchKernelGGL(anew_k, dim3(gM), dim3(TB), 0, stream, rr, cc, tptr, tidx, tk, tv, out + K_ * F_);
  hipLaunchKernelGGL(adiag_k, dim3(1), dim3(TB), 0, stream, out + K_ * F_);

  (void)in_sizes; (void)n_in; (void)out_size; (void)ws_size;
}

// Round 7
// 299.779 us; speedup vs baseline: 2.3377x; 1.1895x over previous
//
#include <hip/hip_runtime.h>
#include <math.h>

// ---------------------------------------------------------------------------
// ASAP pooling block, fixed shapes.
// ---------------------------------------------------------------------------
constexpr int N_ = 20000;
constexpr int E_ = 320000;
constexpr int M_ = E_ + N_;      // edges incl. self loops
constexpr int F_ = 64;
constexpr int K_ = 256;
constexpr int TCAP = 32768;      // S-triplet capacity (expected ~4400)
constexpr int OUT_WORDS = K_ * F_ + K_ * K_ + K_;   // 82176

// ---- workspace layout (word offsets; 16B-aligned where float4-read) -------
constexpr size_t O_CSRC = 0;                           // CSR(by col) source node
constexpr size_t O_CNRM = O_CSRC + M_;                 // CSR gcn norm weight
constexpr size_t O_SC   = O_CNRM + M_;                 // CSR attention exp(score)
constexpr size_t O_BUFA = O_SC + M_;
constexpr size_t O_BUFB = O_BUFA + (size_t)N_ * F_;
constexpr size_t O_BUFC = O_BUFB + (size_t)N_ * F_;
constexpr size_t O_CPTR = O_BUFC + (size_t)N_ * F_;    // N+1 (padded to N+4)
constexpr size_t O_Q2   = O_CPTR + N_ + 4;
constexpr size_t O_DEN  = O_Q2 + N_;
constexpr size_t O_AV   = O_DEN + N_;
constexpr size_t O_BV   = O_AV + N_;
constexpr size_t O_C3   = O_BV + N_;
constexpr size_t O_FIT  = O_C3 + N_;
constexpr size_t O_TPTR = O_FIT + N_;                  // N+1 (padded to N+4)
constexpr size_t O_TI   = O_TPTR + N_ + 4;
constexpr size_t O_TK   = O_TI + TCAP;
constexpr size_t O_TV   = O_TK + TCAP;
constexpr size_t O_TIDX = O_TV + TCAP;
constexpr size_t O_PERM = O_TIDX + TCAP;               // 256 (uint)
constexpr size_t O_FITS = O_PERM + K_;                 // 256 (f32)
constexpr size_t O_WQ   = O_FITS + K_;                 // 65 (lin/att folded vec + bias)
// zero-initialized region:
constexpr size_t O_ZR   = O_WQ + 72;
constexpr size_t O_CNT  = O_ZR;                        // N (in-degree counts)
constexpr size_t O_CUR  = O_CNT + N_;                  // N
constexpr size_t O_TCNT = O_CUR + N_;                  // N
constexpr size_t O_TCUR = O_TCNT + N_;                 // N
constexpr size_t O_CTRL = O_TCUR + N_;                 // 8 (ctrl[5]=trip count)
constexpr size_t ZR_WORDS = O_CTRL + 8 - O_ZR;

__device__ __forceinline__ float4 ld4(const float* p) { return *reinterpret_cast<const float4*>(p); }
__device__ __forceinline__ void st4(float* p, float4 v) { *reinterpret_cast<float4*>(p) = v; }

// ---------------------------------------------------------------------------
__global__ void init_k(unsigned* __restrict__ zr, float* __restrict__ dout) {
  int g = blockIdx.x * blockDim.x + threadIdx.x;
  if (g < (int)ZR_WORDS) zr[g] = 0u;
  if (g < OUT_WORDS) dout[g] = 0.0f;
}

// degree counts; last block also computes wq = linW@attW[:64], wq[64]=linb·attW
__global__ void build_edges_k(const int* __restrict__ ei, unsigned* __restrict__ cnt,
                              const float* __restrict__ linW, const float* __restrict__ linb,
                              const float* __restrict__ attW, float* __restrict__ wq) {
  if (blockIdx.x == gridDim.x - 1) {
    int f = threadIdx.x;
    if (f < 64) {
      float s = 0.0f;
      for (int c = 0; c < 64; ++c) s += linW[f * 64 + c] * attW[c];
      wq[f] = s;
      float b = linb[f] * attW[f];
      for (int off = 32; off; off >>= 1) b += __shfl_down(b, off);
      if (f == 0) wq[64] = b;
    }
    return;
  }
  int g = blockIdx.x * blockDim.x + threadIdx.x;
  if (g >= M_) return;
  int c = (g < E_) ? ei[E_ + g] : g - E_;
  atomicAdd(&cnt[c], 1u);
}

// single-block exclusive prefix (n bins -> ptr[n+1]); LDS-staged, 4 barriers
__global__ __launch_bounds__(1024) void prefix_k(const unsigned* __restrict__ cnt,
                                                 unsigned* __restrict__ ptr, int n) {
  __shared__ unsigned buf[N_];
  __shared__ unsigned wsum[16];
  __shared__ unsigned s_total;
  int t = threadIdx.x;
  int wv = t >> 6, ln = t & 63;
  for (int i = t; i < n; i += 1024) buf[i] = cnt[i];
  __syncthreads();
  int chunk = (n + 1023) >> 10;
  int i0 = t * chunk;
  unsigned s = 0;
  for (int j = 0; j < chunk; ++j) { int i = i0 + j; if (i < n) s += buf[i]; }
  unsigned pre = s;
  for (int off = 1; off < 64; off <<= 1) {
    unsigned v = __shfl_up(pre, off);
    if (ln >= off) pre += v;
  }
  if (ln == 63) wsum[wv] = pre;
  __syncthreads();
  if (t == 0) {
    unsigned run = 0;
    for (int w = 0; w < 16; ++w) { unsigned v = wsum[w]; wsum[w] = run; run += v; }
    s_total = run;
  }
  __syncthreads();
  unsigned run = wsum[wv] + (pre - s);   // exclusive prefix at chunk start
  for (int j = 0; j < chunk; ++j) {
    int i = i0 + j;
    if (i < n) { unsigned v = buf[i]; buf[i] = run; run += v; }
  }
  __syncthreads();
  for (int i = t; i < n; i += 1024) ptr[i] = buf[i];
  if (t == 0) ptr[n] = s_total;
}

// scatter edge -> CSR(by col) position; store src node and gcn norm weight
__global__ void scatter_csr_k(const int* __restrict__ ei,
                              const unsigned* __restrict__ cptr, unsigned* __restrict__ cur,
                              int* __restrict__ csrc, float* __restrict__ cnrm) {
  int g = blockIdx.x * blockDim.x + threadIdx.x;
  if (g >= M_) return;
  int r, c;
  if (g < E_) { r = ei[g]; c = ei[E_ + g]; } else { r = g - E_; c = r; }
  unsigned pos = cptr[c] + atomicAdd(&cur[c], 1u);
  csrc[pos] = r;
  float dr = (float)(cptr[r + 1] - cptr[r]);
  float dc = (float)(cptr[c + 1] - cptr[c]);
  cnrm[pos] = (1.0f / sqrtf(dr)) * (1.0f / sqrtf(dc));
}

// Y[n,64] = X[n,64] @ W[64,64]. Tiled: 64 rows/block, 256 threads.
__global__ void gemm64_k(const float* __restrict__ X, const float* __restrict__ W,
                         float* __restrict__ Y) {
  __shared__ float xs[64][64];
  __shared__ float wsh[64][64];
  int t = threadIdx.x;
  int r0 = blockIdx.x * 64;
  for (int i = 0; i < 16; ++i) {
    int idx = t + i * 256;
    wsh[idx >> 6][idx & 63] = W[idx];
  }
  for (int i = 0; i < 16; ++i) {
    int idx = t + i * 256;
    int r = idx >> 6, c = idx & 63;
    xs[r][c] = (r0 + r < N_) ? X[(size_t)(r0 + r) * F_ + c] : 0.0f;
  }
  __syncthreads();
  int c = t & 63, rg = t >> 6;
  float acc[16];
#pragma unroll
  for (int m = 0; m < 16; ++m) acc[m] = 0.0f;
  for (int k = 0; k < 64; ++k) {
    float w = wsh[k][c];
#pragma unroll
    for (int m = 0; m < 16; ++m) acc[m] += xs[rg + 4 * m][k] * w;
  }
  for (int m = 0; m < 16; ++m) {
    int r = r0 + rg + 4 * m;
    if (r < N_) Y[(size_t)r * F_ + c] = acc[m];
  }
}

// GCN aggregate, vectorized: wave per node; 16 lanes x float4 per row, 4 edges
// in flight. EPI 1: q2[i] = relu_out · attW[64:128].
template<int EPI>
__global__ void agg_gcn_k(const float* __restrict__ H, const int* __restrict__ csrc,
                          const float* __restrict__ wts, const unsigned* __restrict__ cptr,
                          const float* __restrict__ bias, float* __restrict__ Y,
                          const float* __restrict__ attW, float* __restrict__ q2) {
  int wid = blockIdx.x * (blockDim.x >> 6) + (threadIdx.x >> 6);
  int lane = threadIdx.x & 63;
  if (wid >= N_) return;
  int sub = lane >> 4, fq = lane & 15;
  unsigned p0 = cptr[wid], p1 = cptr[wid + 1];
  float ax = 0.f, ay = 0.f, az = 0.f, aw = 0.f;
  for (unsigned p = p0 + sub; p < p1; p += 4) {
    int s = csrc[p];
    float w = wts[p];
    float4 h = ld4(H + (size_t)s * F_ + 4 * fq);
    ax += w * h.x; ay += w * h.y; az += w * h.z; aw += w * h.w;
  }
#pragma unroll
  for (int off = 16; off <= 32; off <<= 1) {
    ax += __shfl_xor(ax, off); ay += __shfl_xor(ay, off);
    az += __shfl_xor(az, off); aw += __shfl_xor(aw, off);
  }
  float4 b4 = ld4(bias + 4 * fq);
  ax = fmaxf(ax + b4.x, 0.f); ay = fmaxf(ay + b4.y, 0.f);
  az = fmaxf(az + b4.z, 0.f); aw = fmaxf(aw + b4.w, 0.f);
  if (sub == 0) { float4 o{ax, ay, az, aw}; st4(Y + (size_t)wid * F_ + 4 * fq, o); }
  if (EPI == 1) {
    float4 a4 = ld4(attW + 64 + 4 * fq);
    float v = ax * a4.x + ay * a4.y + az * a4.z + aw * a4.w;
#pragma unroll
    for (int off = 1; off <= 8; off <<= 1) v += __shfl_xor(v, off);
    if (lane == 0) q2[wid] = v;
  }
}

// Fused attention: segment-max (+folded lin·att -> q1) -> leaky/softmax stats
// -> xc weighted gather (+le1/le2/le3 dots). Wave per node.
__global__ void attn_fused_k(const float* __restrict__ X2, const int* __restrict__ csrc,
                             const unsigned* __restrict__ cptr, const float* __restrict__ q2,
                             const float* __restrict__ attb, const float* __restrict__ wq,
                             float* __restrict__ sc, float* __restrict__ den,
                             float* __restrict__ XC,
                             const float* __restrict__ le1W, const float* __restrict__ le1b,
                             const float* __restrict__ le2W, const float* __restrict__ le3W,
                             const float* __restrict__ le3b, float* __restrict__ av,
                             float* __restrict__ bv, float* __restrict__ c3) {
  int wid = blockIdx.x * (blockDim.x >> 6) + (threadIdx.x >> 6);
  int lane = threadIdx.x & 63;
  if (wid >= N_) return;
  int sub = lane >> 4, fq = lane & 15;
  unsigned p0 = cptr[wid], p1 = cptr[wid + 1];
  // phase A: feature-wise segment max + q1 dot
  float mx = -INFINITY, my = -INFINITY, mz = -INFINITY, mw = -INFINITY;
  for (unsigned p = p0 + sub; p < p1; p += 4) {
    int s = csrc[p];
    float4 h = ld4(X2 + (size_t)s * F_ + 4 * fq);
    mx = fmaxf(mx, h.x); my = fmaxf(my, h.y); mz = fmaxf(mz, h.z); mw = fmaxf(mw, h.w);
  }
#pragma unroll
  for (int off = 16; off <= 32; off <<= 1) {
    mx = fmaxf(mx, __shfl_xor(mx, off)); my = fmaxf(my, __shfl_xor(my, off));
    mz = fmaxf(mz, __shfl_xor(mz, off)); mw = fmaxf(mw, __shfl_xor(mw, off));
  }
  float4 w4 = ld4(wq + 4 * fq);
  float q1v = mx * w4.x + my * w4.y + mz * w4.z + mw * w4.w;
#pragma unroll
  for (int off = 1; off <= 8; off <<= 1) q1v += __shfl_xor(q1v, off);
  float base = q1v + wq[64] + attb[0];
  // phase B: leaky score max, exp-sum; lanes split edges
  float m = -INFINITY;
  for (unsigned p = p0 + lane; p < p1; p += 64) {
    float s = base + q2[csrc[p]];
    s = (s > 0.0f) ? s : 0.2f * s;
    m = fmaxf(m, s);
  }
#pragma unroll
  for (int off = 1; off <= 32; off <<= 1) m = fmaxf(m, __shfl_xor(m, off));
  float d = 0.0f;
  for (unsigned p = p0 + lane; p < p1; p += 64) {
    float s = base + q2[csrc[p]];
    s = (s > 0.0f) ? s : 0.2f * s;
    float e = expf(s - m);
    sc[p] = e;
    d += e;
  }
#pragma unroll
  for (int off = 1; off <= 32; off <<= 1) d += __shfl_xor(d, off);
  if (lane == 0) den[wid] = d;
  // phase C: xc = (sum e*x)/d ; recompute e (bit-identical) to avoid x-lane mem
  float ax = 0.f, ay = 0.f, az = 0.f, aw = 0.f;
  for (unsigned p = p0 + sub; p < p1; p += 4) {
    int s = csrc[p];
    float sv = base + q2[s];
    sv = (sv > 0.0f) ? sv : 0.2f * sv;
    float w = expf(sv - m);
    float4 h = ld4(X2 + (size_t)s * F_ + 4 * fq);
    ax += w * h.x; ay += w * h.y; az += w * h.z; aw += w * h.w;
  }
#pragma unroll
  for (int off = 16; off <= 32; off <<= 1) {
    ax += __shfl_xor(ax, off); ay += __shfl_xor(ay, off);
    az += __shfl_xor(az, off); aw += __shfl_xor(aw, off);
  }
  float inv = 1.0f / d;
  ax *= inv; ay *= inv; az *= inv; aw *= inv;
  if (sub == 0) { float4 o{ax, ay, az, aw}; st4(XC + (size_t)wid * F_ + 4 * fq, o); }
  float4 l1 = ld4(le1W + 4 * fq), l2 = ld4(le2W + 4 * fq), l3 = ld4(le3W + 4 * fq);
  float s1 = ax * l1.x + ay * l1.y + az * l1.z + aw * l1.w;
  float s2 = ax * l2.x + ay * l2.y + az * l2.z + aw * l2.w;
  float s3 = ax * l3.x + ay * l3.y + az * l3.z + aw * l3.w;
#pragma unroll
  for (int off = 1; off <= 8; off <<= 1) {
    s1 += __shfl_xor(s1, off); s2 += __shfl_xor(s2, off); s3 += __shfl_xor(s3, off);
  }
  if (lane == 0) { av[wid] = s1 + le1b[0]; bv[wid] = s2; c3[wid] = s3 + le3b[0]; }
}

// fitness: wave per node, lanes split edges
__global__ void fitness_k(const unsigned* __restrict__ cptr, const int* __restrict__ csrc,
                          const float* __restrict__ av, const float* __restrict__ bv,
                          const float* __restrict__ c3, float* __restrict__ fit) {
  int wid = blockIdx.x * (blockDim.x >> 6) + (threadIdx.x >> 6);
  int lane = threadIdx.x & 63;
  if (wid >= N_) return;
  unsigned p0 = cptr[wid], p1 = cptr[wid + 1];
  float s = 0.0f;
  for (unsigned p = p0 + lane; p < p1; p += 64) s += av[csrc[p]];
#pragma unroll
  for (int off = 1; off <= 32; off <<= 1) s += __shfl_xor(s, off);
  if (lane == 0) {
    float deg = (float)(p1 - p0);
    float val = s - deg * bv[wid] + c3[wid];
    fit[wid] = 1.0f / (1.0f + expf(-val));
  }
}

// ---------------------------------------------------------------------------
// Single-block exact top-K v3: fit bits staged in LDS; 4x8-bit radix select
// (fit>0 so bit order == value order); single-wave shfl scans; exact
// smallest-index tie-break; rank-sort of the 256 winners. ~25 barriers total.
// ---------------------------------------------------------------------------
__global__ __launch_bounds__(1024) void topk_k(const float* __restrict__ fit,
                                               unsigned* __restrict__ perm_i,
                                               float* __restrict__ fit_s,
                                               float* __restrict__ out_perm) {
  __shared__ unsigned fb_s[N_];          // 80000 B (gfx950: 160 KiB LDS/CU)
  __shared__ unsigned hist[256 * 16];    // 16384 B
  __shared__ unsigned scn[256];
  __shared__ unsigned long long keys[K_];
  __shared__ unsigned rnk[K_];
  __shared__ unsigned s_pfx, s_rem, s_cnt, s_bstar, s_rem2, s_cut, s_all;
  int t = threadIdx.x;
  int sub = t & 15;
  int wv = t >> 6, ln = t & 63;

  for (int i = t; i < N_; i += 1024) fb_s[i] = __float_as_uint(fit[i]);
  if (t == 0) { s_cnt = 0; s_all = 0; }
  if (t < K_) rnk[t] = 0;
  __syncthreads();

  unsigned msk = 0, pfx = 0, rem = K_;
  for (int lvl = 0; lvl < 4; ++lvl) {
    const int shift = 24 - lvl * 8;
    for (int i = t; i < 256 * 16; i += 1024) hist[i] = 0;
    __syncthreads();
    for (int i = t; i < N_; i += 1024) {
      unsigned fb = fb_s[i];
      if ((fb & msk) == pfx)
        atomicAdd(&hist[(((fb >> shift) & 0xFF) << 4) + sub], 1u);
    }
    __syncthreads();
    if (t < 256) {
      unsigned h = 0;
#pragma unroll
      for (int s = 0; s < 16; ++s) h += hist[(t << 4) + s];
      scn[t] = h;
    }
    __syncthreads();
    if (wv == 0) {  // suffix-scan 256 bins in one wave (4 bins/lane)
      unsigned b0 = scn[4 * ln], b1 = scn[4 * ln + 1], b2 = scn[4 * ln + 2], b3 = scn[4 * ln + 3];
      unsigned loc = b0 + b1 + b2 + b3;
      unsigned suf = loc;
      for (int off = 1; off < 64; off <<= 1) {
        unsigned v = __shfl_down(suf, off);
        if (ln + off < 64) suf += v;
      }
      unsigned above = suf - loc;          // sum of bins > 4ln+3
      unsigned s3 = above + b3;
      unsigned s2 = s3 + b2;
      unsigned s1 = s2 + b1;
      unsigned s0 = s1 + b0;
      if (s0 >= rem && s1 < rem)    { s_pfx = pfx | ((unsigned)(4 * ln)     << shift); s_rem = rem - s1; }
      if (s1 >= rem && s2 < rem)    { s_pfx = pfx | ((unsigned)(4 * ln + 1) << shift); s_rem = rem - s2; }
      if (s2 >= rem && s3 < rem)    { s_pfx = pfx | ((unsigned)(4 * ln + 2) << shift); s_rem = rem - s3; }
      if (s3 >= rem && above < rem) { s_pfx = pfx | ((unsigned)(4 * ln + 3) << shift); s_rem = rem - above; }
    }
    __syncthreads();
    pfx = s_pfx; rem = s_rem; msk |= (0xFFu << shift);
  }
  // pfx = exact bits of K-th largest; rem = #ties to take (smallest indices).
  for (int i = t; i < 256 * 16; i += 1024) hist[i] = 0;
  __syncthreads();
  // fused: emit strict winners + histogram ties by idx>>7 (157 bins)
  for (int i = t; i < N_; i += 1024) {
    unsigned fb = fb_s[i];
    if (fb > pfx) {
      unsigned j = atomicAdd(&s_cnt, 1u);
      keys[j] = ((unsigned long long)fb << 32) | (unsigned long long)(0xFFFFFFFFu - (unsigned)i);
    } else if (fb == pfx) {
      atomicAdd(&hist[((i >> 7) << 4) + sub], 1u);
    }
  }
  __syncthreads();
  if (t < 256) {
    unsigned h = 0;
#pragma unroll
    for (int s = 0; s < 16; ++s) h += hist[(t << 4) + s];
    scn[t] = h;
  }
  __syncthreads();
  if (wv == 0) {  // prefix-scan 256 bins in one wave
    unsigned b0 = scn[4 * ln], b1 = scn[4 * ln + 1], b2 = scn[4 * ln + 2], b3 = scn[4 * ln + 3];
    unsigned loc = b0 + b1 + b2 + b3;
    unsigned pre = loc;
    for (int off = 1; off < 64; off <<= 1) {
      unsigned v = __shfl_up(pre, off);
      if (ln >= off) pre += v;
    }
    unsigned below = pre - loc;
    unsigned p0 = below + b0;
    unsigned p1 = p0 + b1;
    unsigned p2 = p1 + b2;
    unsigned p3 = p2 + b3;
    if (ln == 63 && p3 == rem) s_all = 1u;   // all ties taken
    if (p0 >= rem && below < rem) { s_bstar = 4u * ln;     s_rem2 = rem - below; }
    if (p1 >= rem && p0 < rem)    { s_bstar = 4u * ln + 1; s_rem2 = rem - p0; }
    if (p2 >= rem && p1 < rem)    { s_bstar = 4u * ln + 2; s_rem2 = rem - p1; }
    if (p3 >= rem && p2 < rem)    { s_bstar = 4u * ln + 3; s_rem2 = rem - p2; }
  }
  __syncthreads();
  unsigned bstar = s_bstar, rem2 = s_rem2;
  if (s_all) {
    for (int i = t; i < N_; i += 1024)
      if (fb_s[i] == pfx) {
        unsigned j = atomicAdd(&s_cnt, 1u);
        keys[j] = ((unsigned long long)pfx << 32) | (unsigned long long)(0xFFFFFFFFu - (unsigned)i);
      }
  } else {
    // tie level B: bins = idx & 127 within bstar (unique -> h in {0,1})
    for (int i = t; i < 256 * 16; i += 1024) hist[i] = 0;
    __syncthreads();
    for (int i = t; i < N_; i += 1024)
      if (fb_s[i] == pfx && (unsigned)(i >> 7) == bstar)
        atomicAdd(&hist[((i & 127) << 4) + sub], 1u);
    __syncthreads();
    if (t < 128) {
      unsigned h = 0;
#pragma unroll
      for (int s = 0; s < 16; ++s) h += hist[(t << 4) + s];
      scn[t] = h;
    }
    __syncthreads();
    if (wv == 0) {  // prefix-scan 128 bins (2/lane)
      unsigned b0 = scn[2 * ln], b1 = scn[2 * ln + 1];
      unsigned loc = b0 + b1;
      unsigned pre = loc;
      for (int off = 1; off < 64; off <<= 1) {
        unsigned v = __shfl_up(pre, off);
        if (ln >= off) pre += v;
      }
      unsigned below = pre - loc;
      unsigned p0 = below + b0;
      unsigned p1 = p0 + b1;
      if (p0 >= rem2 && below < rem2) s_cut = 2u * ln;
      if (p1 >= rem2 && p0 < rem2)    s_cut = 2u * ln + 1;
    }
    __syncthreads();
    unsigned cut = s_cut;
    for (int i = t; i < N_; i += 1024) {
      if (fb_s[i] == pfx) {
        unsigned hi = (unsigned)(i >> 7), lo = (unsigned)(i & 127);
        if (hi < bstar || (hi == bstar && lo <= cut)) {
          unsigned j = atomicAdd(&s_cnt, 1u);
          keys[j] = ((unsigned long long)pfx << 32) | (unsigned long long)(0xFFFFFFFFu - (unsigned)i);
        }
      }
    }
  }
  __syncthreads();
  // rank sort: 1024 threads, key t&255, segment t>>8 (64 comparisons each)
  {
    int k = t & 255, seg = t >> 8;
    unsigned long long my = keys[k];
    unsigned r = 0;
    for (int j = seg * 64; j < seg * 64 + 64; ++j) r += (keys[j] > my) ? 1u : 0u;
    if (r) atomicAdd(&rnk[k], r);
  }
  __syncthreads();
  if (t < K_) {
    unsigned long long kk = keys[t];
    unsigned r = rnk[t];
    unsigned idx = 0xFFFFFFFFu - (unsigned)(kk & 0xFFFFFFFFu);
    perm_i[r] = idx;
    fit_s[r] = __uint_as_float((unsigned)(kk >> 32));
    out_perm[r] = (float)idx;
  }
}

__global__ void xnew_k(const float* __restrict__ XC, const unsigned* __restrict__ perm_i,
                       const float* __restrict__ fit_s, float* __restrict__ out) {
  int g = blockIdx.x * blockDim.x + threadIdx.x;
  if (g >= K_ * F_ / 4) return;
  int k = g >> 4, fq = g & 15;
  float4 v = ld4(XC + (size_t)perm_i[k] * F_ + 4 * fq);
  float f = fit_s[k];
  v.x *= f; v.y *= f; v.z *= f; v.w *= f;
  st4(out + (size_t)k * F_ + 4 * fq, v);
}

// build S triplets directly from the 256 selected nodes' CSR ranges
__global__ void trip_sel_k(const unsigned* __restrict__ perm_i, const unsigned* __restrict__ cptr,
                           const int* __restrict__ csrc, const float* __restrict__ sc,
                           const float* __restrict__ den,
                           int* __restrict__ ti, int* __restrict__ tk, float* __restrict__ tv,
                           unsigned* __restrict__ tcnt, unsigned* __restrict__ ctrl) {
  int k = blockIdx.x * blockDim.x + threadIdx.x;
  if (k >= K_) return;
  unsigned i = perm_i[k];
  unsigned p0 = cptr[i], p1 = cptr[i + 1];
  float d = den[i];
  for (unsigned p = p0; p < p1; ++p) {
    unsigned j = atomicAdd(&ctrl[5], 1u);
    if (j < (unsigned)TCAP) {
      int r = csrc[p];
      ti[j] = r; tk[j] = k; tv[j] = sc[p] / d;
      atomicAdd(&tcnt[r], 1u);
    }
  }
}

__global__ void trip_scatter_k(const int* __restrict__ ti, const unsigned* __restrict__ tptr,
                               unsigned* __restrict__ tcur, unsigned* __restrict__ tidx,
                               const unsigned* __restrict__ ctrl) {
  int g = blockIdx.x * blockDim.x + threadIdx.x;
  unsigned cnt = ctrl[5]; if (cnt > (unsigned)TCAP) cnt = TCAP;
  if (g >= (int)cnt) return;
  int i = ti[g];
  unsigned pos = tptr[i] + atomicAdd(&tcur[i], 1u);
  tidx[pos] = (unsigned)g;
}

// A[k1,k2] += sum over edges of S[row,k1]*S[col,k2]
__global__ void anew_k(const int* __restrict__ ei,
                       const unsigned* __restrict__ tptr, const unsigned* __restrict__ tidx,
                       const int* __restrict__ tk, const float* __restrict__ tv,
                       float* __restrict__ A) {
  int g = blockIdx.x * blockDim.x + threadIdx.x;
  if (g >= M_) return;
  int i, j;
  if (g < E_) { i = ei[g]; j = ei[E_ + g]; } else { i = j = g - E_; }
  unsigned a0 = tptr[i], a1 = tptr[i + 1];
  if (a0 == a1) return;
  unsigned b0 = tptr[j], b1 = tptr[j + 1];
  if (b0 == b1) return;
  for (unsigned pa = a0; pa < a1; ++pa) {
    unsigned ta = tidx[pa];
    int k1 = tk[ta];
    float va = tv[ta];
    float* Arow = A + (size_t)k1 * K_;
    for (unsigned pb = b0; pb < b1; ++pb) {
      unsigned tb = tidx[pb];
      atomicAdd(&Arow[tk[tb]], va * tv[tb]);
    }
  }
}

__global__ void adiag_k(float* __restrict__ A) {
  int t = threadIdx.x;
  if (t < K_) A[(size_t)t * K_ + t] = 1.0f;
}

// ---------------------------------------------------------------------------
extern "C" void kernel_launch(void* const* d_in, const int* in_sizes, int n_in,
                              void* d_out, int out_size, void* d_ws, size_t ws_size,
                              hipStream_t stream) {
  const float* x     = (const float*)d_in[0];
  const int*   ei    = (const int*)d_in[1];
  const float* W0    = (const float*)d_in[2];
  const float* b0    = (const float*)d_in[3];
  const float* W1    = (const float*)d_in[4];
  const float* b1    = (const float*)d_in[5];
  const float* linW  = (const float*)d_in[6];
  const float* linb  = (const float*)d_in[7];
  const float* attW  = (const float*)d_in[8];
  const float* attb  = (const float*)d_in[9];
  const float* le1W  = (const float*)d_in[10];
  const float* le1b  = (const float*)d_in[11];
  const float* le2W  = (const float*)d_in[12];
  const float* le3W  = (const float*)d_in[13];
  const float* le3b  = (const float*)d_in[14];

  float*    wf = (float*)d_ws;
  unsigned* wu = (unsigned*)d_ws;
  int*      wi = (int*)d_ws;
  float*    out = (float*)d_out;

  int*      csrc  = wi + O_CSRC;
  float*    cnrm  = wf + O_CNRM;
  float*    sc    = wf + O_SC;
  float*    bufA  = wf + O_BUFA;
  float*    bufB  = wf + O_BUFB;
  float*    bufC  = wf + O_BUFC;
  unsigned* cptr  = wu + O_CPTR;
  float*    q2    = wf + O_Q2;
  float*    den   = wf + O_DEN;
  float*    av    = wf + O_AV;
  float*    bv    = wf + O_BV;
  float*    c3    = wf + O_C3;
  float*    fit   = wf + O_FIT;
  unsigned* tptr  = wu + O_TPTR;
  int*      ti    = wi + O_TI;
  int*      tk    = wi + O_TK;
  float*    tv    = wf + O_TV;
  unsigned* tidx  = wu + O_TIDX;
  unsigned* perm_i= wu + O_PERM;
  float*    fit_s = wf + O_FITS;
  float*    wq    = wf + O_WQ;
  unsigned* zr    = wu + O_ZR;
  unsigned* cnt   = wu + O_CNT;
  unsigned* cur   = wu + O_CUR;
  unsigned* tcnt  = wu + O_TCNT;
  unsigned* tcur  = wu + O_TCUR;
  unsigned* ctrl  = wu + O_CTRL;

  const int TB = 256;
  const int gM = (M_ + TB - 1) / TB;          // 1329
  const int gW = (N_ + 3) / 4;                // 5000 (wave-per-node, 4 waves/block)
  const int gG = (N_ + 63) / 64;              // 313 (gemm tiles)
  const int gZ = ((int)(ZR_WORDS > OUT_WORDS ? ZR_WORDS : OUT_WORDS) + TB - 1) / TB;

  hipLaunchKernelGGL(init_k, dim3(gZ), dim3(TB), 0, stream, zr, out);
  hipLaunchKernelGGL(build_edges_k, dim3(gM + 1), dim3(TB), 0, stream, ei, cnt,
                     linW, linb, attW, wq);
  hipLaunchKernelGGL(prefix_k, dim3(1), dim3(1024), 0, stream, cnt, cptr, N_);
  hipLaunchKernelGGL(scatter_csr_k, dim3(gM), dim3(TB), 0, stream, ei, cptr, cur, csrc, cnrm);

  // GCN layer 1: bufA = x@W0 ; bufB = relu(agg + b0)
  hipLaunchKernelGGL(gemm64_k, dim3(gG), dim3(TB), 0, stream, x, W0, bufA);
  hipLaunchKernelGGL((agg_gcn_k<0>), dim3(gW), dim3(TB), 0, stream, bufA, csrc, cnrm, cptr, b0, bufB,
                     nullptr, nullptr);
  // GCN layer 2: bufA = bufB@W1 ; bufC = relu(agg + b1) = x2 ; q2 epilogue
  hipLaunchKernelGGL(gemm64_k, dim3(gG), dim3(TB), 0, stream, bufB, W1, bufA);
  hipLaunchKernelGGL((agg_gcn_k<1>), dim3(gW), dim3(TB), 0, stream, bufA, csrc, cnrm, cptr, b1, bufC,
                     attW, q2);

  // fused attention pooling (xc -> bufB) + le dots
  hipLaunchKernelGGL(attn_fused_k, dim3(gW), dim3(TB), 0, stream, bufC, csrc, cptr, q2, attb, wq,
                     sc, den, bufB, le1W, le1b, le2W, le3W, le3b, av, bv, c3);

  // fitness + exact top-K
  hipLaunchKernelGGL(fitness_k, dim3(gW), dim3(TB), 0, stream, cptr, csrc, av, bv, c3, fit);
  hipLaunchKernelGGL(topk_k, dim3(1), dim3(1024), 0, stream, fit, perm_i, fit_s, out + K_ * F_ + K_ * K_);
  hipLaunchKernelGGL(xnew_k, dim3((K_ * F_ / 4 + TB - 1) / TB), dim3(TB), 0, stream, bufB, perm_i, fit_s, out);

  // sparse S triplets -> A_new
  hipLaunchKernelGGL(trip_sel_k, dim3(1), dim3(TB), 0, stream, perm_i, cptr, csrc, sc, den, ti, tk, tv, tcnt, ctrl);
  hipLaunchKernelGGL(prefix_k, dim3(1), dim3(1024), 0, stream, tcnt, tptr, N_);
  hipLaunchKernelGGL(trip_scatter_k, dim3(TCAP / TB), dim3(TB), 0, stream, ti, tptr, tcur, tidx, ctrl);
  hipLaunchKernelGGL(anew_k, dim3(gM), dim3(TB), 0, stream, ei, tptr, tidx, tk, tv, out + K_ * F_);
  hipLaunchKernelGGL(adiag_k, dim3(1), dim3(TB), 0, stream, out + K_ * F_);

  (void)in_sizes; (void)n_in; (void)out_size; (void)ws_size;
}

// Round 8
// 287.761 us; speedup vs baseline: 2.4354x; 1.0418x over previous
//
#include <hip/hip_runtime.h>
#include <math.h>

// ---------------------------------------------------------------------------
// ASAP pooling block, fixed shapes.
// ---------------------------------------------------------------------------
constexpr int N_ = 20000;
constexpr int E_ = 320000;
constexpr int M_ = E_ + N_;      // edges incl. self loops
constexpr int F_ = 64;
constexpr int K_ = 256;
constexpr int TCAP = 32768;      // S-triplet capacity (expected ~4400)
constexpr int OUT_WORDS = K_ * F_ + K_ * K_ + K_;   // 82176

// ---- workspace layout (word offsets; 16B-aligned where float4-read) -------
constexpr size_t O_CSRC = 0;                           // CSR(by col) source node
constexpr size_t O_CNRM = O_CSRC + M_;                 // CSR gcn norm weight
constexpr size_t O_SC   = O_CNRM + M_;                 // CSR attention exp(score)
constexpr size_t O_BUFA = O_SC + M_;
constexpr size_t O_BUFB = O_BUFA + (size_t)N_ * F_;
constexpr size_t O_BUFC = O_BUFB + (size_t)N_ * F_;
constexpr size_t O_CPTR = O_BUFC + (size_t)N_ * F_;    // N+1 (padded to N+4)
constexpr size_t O_Q2   = O_CPTR + N_ + 4;
constexpr size_t O_DEN  = O_Q2 + N_;
constexpr size_t O_AV   = O_DEN + N_;
constexpr size_t O_BV   = O_AV + N_;
constexpr size_t O_C3   = O_BV + N_;
constexpr size_t O_FIT  = O_C3 + N_;
constexpr size_t O_TPTR = O_FIT + N_;                  // N+1 (padded to N+4)
constexpr size_t O_TI   = O_TPTR + N_ + 4;
constexpr size_t O_TK   = O_TI + TCAP;
constexpr size_t O_TV   = O_TK + TCAP;
constexpr size_t O_TIDX = O_TV + TCAP;
constexpr size_t O_PERM = O_TIDX + TCAP;               // 256 (uint)
constexpr size_t O_FITS = O_PERM + K_;                 // 256 (f32)
constexpr size_t O_WQ   = O_FITS + K_;                 // 65 (lin/att folded vec + bias)
// zero-initialized region:
constexpr size_t O_ZR   = O_WQ + 72;
constexpr size_t O_CNT  = O_ZR;                        // N (in-degree counts)
constexpr size_t O_CUR  = O_CNT + N_;                  // N
constexpr size_t O_TCNT = O_CUR + N_;                  // N
constexpr size_t O_TCUR = O_TCNT + N_;                 // N
constexpr size_t O_CTRL = O_TCUR + N_;                 // 8 (ctrl[5]=trip count)
constexpr size_t ZR_WORDS = O_CTRL + 8 - O_ZR;

__device__ __forceinline__ float4 ld4(const float* p) { return *reinterpret_cast<const float4*>(p); }
__device__ __forceinline__ void st4(float* p, float4 v) { *reinterpret_cast<float4*>(p) = v; }

// ---------------------------------------------------------------------------
__global__ void init_k(unsigned* __restrict__ zr, float* __restrict__ dout) {
  int g = blockIdx.x * blockDim.x + threadIdx.x;
  if (g < (int)ZR_WORDS) zr[g] = 0u;
  if (g < OUT_WORDS) dout[g] = 0.0f;
}

// degree counts; last block also computes wq = linW@attW[:64], wq[64]=linb·attW
__global__ void build_edges_k(const int* __restrict__ ei, unsigned* __restrict__ cnt,
                              const float* __restrict__ linW, const float* __restrict__ linb,
                              const float* __restrict__ attW, float* __restrict__ wq) {
  if (blockIdx.x == gridDim.x - 1) {
    int f = threadIdx.x;
    if (f < 64) {
      float s = 0.0f;
      for (int c = 0; c < 64; ++c) s += linW[f * 64 + c] * attW[c];
      wq[f] = s;
      float b = linb[f] * attW[f];
      for (int off = 32; off; off >>= 1) b += __shfl_down(b, off);
      if (f == 0) wq[64] = b;
    }
    return;
  }
  int g = blockIdx.x * blockDim.x + threadIdx.x;
  if (g >= M_) return;
  int c = (g < E_) ? ei[E_ + g] : g - E_;
  atomicAdd(&cnt[c], 1u);
}

// single-block exclusive prefix (n bins -> ptr[n+1]); LDS-staged, 4 barriers
__global__ __launch_bounds__(1024) void prefix_k(const unsigned* __restrict__ cnt,
                                                 unsigned* __restrict__ ptr, int n) {
  __shared__ unsigned buf[N_];
  __shared__ unsigned wsum[16];
  __shared__ unsigned s_total;
  int t = threadIdx.x;
  int wv = t >> 6, ln = t & 63;
  for (int i = t; i < n; i += 1024) buf[i] = cnt[i];
  __syncthreads();
  int chunk = (n + 1023) >> 10;
  int i0 = t * chunk;
  unsigned s = 0;
  for (int j = 0; j < chunk; ++j) { int i = i0 + j; if (i < n) s += buf[i]; }
  unsigned pre = s;
  for (int off = 1; off < 64; off <<= 1) {
    unsigned v = __shfl_up(pre, off);
    if (ln >= off) pre += v;
  }
  if (ln == 63) wsum[wv] = pre;
  __syncthreads();
  if (t == 0) {
    unsigned run = 0;
    for (int w = 0; w < 16; ++w) { unsigned v = wsum[w]; wsum[w] = run; run += v; }
    s_total = run;
  }
  __syncthreads();
  unsigned run = wsum[wv] + (pre - s);   // exclusive prefix at chunk start
  for (int j = 0; j < chunk; ++j) {
    int i = i0 + j;
    if (i < n) { unsigned v = buf[i]; buf[i] = run; run += v; }
  }
  __syncthreads();
  for (int i = t; i < n; i += 1024) ptr[i] = buf[i];
  if (t == 0) ptr[n] = s_total;
}

// scatter edge -> CSR(by col) position; store src node and gcn norm weight
__global__ void scatter_csr_k(const int* __restrict__ ei,
                              const unsigned* __restrict__ cptr, unsigned* __restrict__ cur,
                              int* __restrict__ csrc, float* __restrict__ cnrm) {
  int g = blockIdx.x * blockDim.x + threadIdx.x;
  if (g >= M_) return;
  int r, c;
  if (g < E_) { r = ei[g]; c = ei[E_ + g]; } else { r = g - E_; c = r; }
  unsigned pos = cptr[c] + atomicAdd(&cur[c], 1u);
  csrc[pos] = r;
  float dr = (float)(cptr[r + 1] - cptr[r]);
  float dc = (float)(cptr[c + 1] - cptr[c]);
  cnrm[pos] = (1.0f / sqrtf(dr)) * (1.0f / sqrtf(dc));
}

// Y[n,64] = X[n,64] @ W[64,64]. Tiled: 64 rows/block, 256 threads.
__global__ void gemm64_k(const float* __restrict__ X, const float* __restrict__ W,
                         float* __restrict__ Y) {
  __shared__ float xs[64][64];
  __shared__ float wsh[64][64];
  int t = threadIdx.x;
  int r0 = blockIdx.x * 64;
  for (int i = 0; i < 16; ++i) {
    int idx = t + i * 256;
    wsh[idx >> 6][idx & 63] = W[idx];
  }
  for (int i = 0; i < 16; ++i) {
    int idx = t + i * 256;
    int r = idx >> 6, c = idx & 63;
    xs[r][c] = (r0 + r < N_) ? X[(size_t)(r0 + r) * F_ + c] : 0.0f;
  }
  __syncthreads();
  int c = t & 63, rg = t >> 6;
  float acc[16];
#pragma unroll
  for (int m = 0; m < 16; ++m) acc[m] = 0.0f;
  for (int k = 0; k < 64; ++k) {
    float w = wsh[k][c];
#pragma unroll
    for (int m = 0; m < 16; ++m) acc[m] += xs[rg + 4 * m][k] * w;
  }
  for (int m = 0; m < 16; ++m) {
    int r = r0 + rg + 4 * m;
    if (r < N_) Y[(size_t)r * F_ + c] = acc[m];
  }
}

// GCN aggregate: wave per node; edge indices/weights coalesced into registers,
// broadcast via shfl; 16 lanes x float4 per row, 4 edges in flight.
// EPI 1: q2[i] = relu_out · attW[64:128].
template<int EPI>
__global__ void agg_gcn_k(const float* __restrict__ H, const int* __restrict__ csrc,
                          const float* __restrict__ wts, const unsigned* __restrict__ cptr,
                          const float* __restrict__ bias, float* __restrict__ Y,
                          const float* __restrict__ attW, float* __restrict__ q2) {
  int wid = blockIdx.x * (blockDim.x >> 6) + (threadIdx.x >> 6);
  int lane = threadIdx.x & 63;
  if (wid >= N_) return;
  int sub = lane >> 4, fq = lane & 15;
  unsigned p0 = cptr[wid], p1 = cptr[wid + 1];
  float ax = 0.f, ay = 0.f, az = 0.f, aw = 0.f;
  for (unsigned base = p0; base < p1; base += 64) {
    int cnt = (int)min(64u, p1 - base);
    int myS = (lane < cnt) ? csrc[base + lane] : 0;
    float myW = (lane < cnt) ? wts[base + lane] : 0.0f;
    for (int e = 0; e < cnt; e += 4) {
      int idx = e + sub;
      int s_e = __shfl(myS, idx);
      float w_e = __shfl(myW, idx);
      if (idx < cnt) {
        float4 h = ld4(H + ((size_t)s_e << 6) + 4 * fq);
        ax += w_e * h.x; ay += w_e * h.y; az += w_e * h.z; aw += w_e * h.w;
      }
    }
  }
#pragma unroll
  for (int off = 16; off <= 32; off <<= 1) {
    ax += __shfl_xor(ax, off); ay += __shfl_xor(ay, off);
    az += __shfl_xor(az, off); aw += __shfl_xor(aw, off);
  }
  float4 b4 = ld4(bias + 4 * fq);
  ax = fmaxf(ax + b4.x, 0.f); ay = fmaxf(ay + b4.y, 0.f);
  az = fmaxf(az + b4.z, 0.f); aw = fmaxf(aw + b4.w, 0.f);
  if (sub == 0) { float4 o{ax, ay, az, aw}; st4(Y + ((size_t)wid << 6) + 4 * fq, o); }
  if (EPI == 1) {
    float4 a4 = ld4(attW + 64 + 4 * fq);
    float v = ax * a4.x + ay * a4.y + az * a4.z + aw * a4.w;
#pragma unroll
    for (int off = 1; off <= 8; off <<= 1) v += __shfl_xor(v, off);
    if (lane == 0) q2[wid] = v;
  }
}

// Fused attention: segment-max (+folded lin·att -> q1) -> leaky/softmax stats
// -> xc weighted gather (+le1/le2/le3 dots). Wave per node.
// Fast path deg<=64: edge ids + e-values live in registers across phases.
__global__ void attn_fused_k(const float* __restrict__ X2, const int* __restrict__ csrc,
                             const unsigned* __restrict__ cptr, const float* __restrict__ q2,
                             const float* __restrict__ attb, const float* __restrict__ wq,
                             float* __restrict__ sc, float* __restrict__ den,
                             float* __restrict__ XC,
                             const float* __restrict__ le1W, const float* __restrict__ le1b,
                             const float* __restrict__ le2W, const float* __restrict__ le3W,
                             const float* __restrict__ le3b, float* __restrict__ av,
                             float* __restrict__ bv, float* __restrict__ c3) {
  int wid = blockIdx.x * (blockDim.x >> 6) + (threadIdx.x >> 6);
  int lane = threadIdx.x & 63;
  if (wid >= N_) return;
  int sub = lane >> 4, fq = lane & 15;
  unsigned p0 = cptr[wid], p1 = cptr[wid + 1];
  int deg = (int)(p1 - p0);
  float ax = 0.f, ay = 0.f, az = 0.f, aw = 0.f;   // phase-C accumulator
  float d;                                         // softmax denom

  if (deg <= 64) {
    int myS = (lane < deg) ? csrc[p0 + lane] : 0;
    // phase A: feature-wise segment max (4 edges in flight)
    float mx = -INFINITY, my = -INFINITY, mz = -INFINITY, mw = -INFINITY;
    for (int e = 0; e < deg; e += 4) {
      int idx = e + sub;
      int s_e = __shfl(myS, idx);
      if (idx < deg) {
        float4 h = ld4(X2 + ((size_t)s_e << 6) + 4 * fq);
        mx = fmaxf(mx, h.x); my = fmaxf(my, h.y); mz = fmaxf(mz, h.z); mw = fmaxf(mw, h.w);
      }
    }
#pragma unroll
    for (int off = 16; off <= 32; off <<= 1) {
      mx = fmaxf(mx, __shfl_xor(mx, off)); my = fmaxf(my, __shfl_xor(my, off));
      mz = fmaxf(mz, __shfl_xor(mz, off)); mw = fmaxf(mw, __shfl_xor(mw, off));
    }
    float4 w4 = ld4(wq + 4 * fq);
    float q1v = mx * w4.x + my * w4.y + mz * w4.z + mw * w4.w;
#pragma unroll
    for (int off = 1; off <= 8; off <<= 1) q1v += __shfl_xor(q1v, off);
    float base = q1v + wq[64] + attb[0];
    // phase B: per-lane edge score -> max -> e -> denom (e stays in reg)
    float sv = -INFINITY;
    if (lane < deg) {
      float s = base + q2[myS];
      sv = (s > 0.0f) ? s : 0.2f * s;
    }
    float m = sv;
#pragma unroll
    for (int off = 1; off <= 32; off <<= 1) m = fmaxf(m, __shfl_xor(m, off));
    float e_l = (lane < deg) ? expf(sv - m) : 0.0f;
    d = e_l;
#pragma unroll
    for (int off = 1; off <= 32; off <<= 1) d += __shfl_xor(d, off);
    if (lane < deg) sc[p0 + lane] = e_l;      // coalesced store
    if (lane == 0) den[wid] = d;
    // phase C: weighted gather; weights broadcast from registers
    for (int e = 0; e < deg; e += 4) {
      int idx = e + sub;
      int s_e = __shfl(myS, idx);
      float w_e = __shfl(e_l, idx);
      if (idx < deg) {
        float4 h = ld4(X2 + ((size_t)s_e << 6) + 4 * fq);
        ax += w_e * h.x; ay += w_e * h.y; az += w_e * h.z; aw += w_e * h.w;
      }
    }
  } else {
    // slow general path (deg > 64): chunked, sc round-trips through memory
    float mx = -INFINITY, my = -INFINITY, mz = -INFINITY, mw = -INFINITY;
    for (unsigned p = p0 + sub; p < p1; p += 4) {
      int s = csrc[p];
      float4 h = ld4(X2 + ((size_t)s << 6) + 4 * fq);
      mx = fmaxf(mx, h.x); my = fmaxf(my, h.y); mz = fmaxf(mz, h.z); mw = fmaxf(mw, h.w);
    }
#pragma unroll
    for (int off = 16; off <= 32; off <<= 1) {
      mx = fmaxf(mx, __shfl_xor(mx, off)); my = fmaxf(my, __shfl_xor(my, off));
      mz = fmaxf(mz, __shfl_xor(mz, off)); mw = fmaxf(mw, __shfl_xor(mw, off));
    }
    float4 w4 = ld4(wq + 4 * fq);
    float q1v = mx * w4.x + my * w4.y + mz * w4.z + mw * w4.w;
#pragma unroll
    for (int off = 1; off <= 8; off <<= 1) q1v += __shfl_xor(q1v, off);
    float base = q1v + wq[64] + attb[0];
    float m = -INFINITY;
    for (unsigned p = p0 + lane; p < p1; p += 64) {
      float s = base + q2[csrc[p]];
      s = (s > 0.0f) ? s : 0.2f * s;
      m = fmaxf(m, s);
    }
#pragma unroll
    for (int off = 1; off <= 32; off <<= 1) m = fmaxf(m, __shfl_xor(m, off));
    d = 0.0f;
    for (unsigned p = p0 + lane; p < p1; p += 64) {
      float s = base + q2[csrc[p]];
      s = (s > 0.0f) ? s : 0.2f * s;
      float e = expf(s - m);
      sc[p] = e;
      d += e;
    }
#pragma unroll
    for (int off = 1; off <= 32; off <<= 1) d += __shfl_xor(d, off);
    if (lane == 0) den[wid] = d;
    for (unsigned p = p0 + sub; p < p1; p += 4) {
      int s = csrc[p];
      float w = sc[p];     // broadcast load (written above)
      float4 h = ld4(X2 + ((size_t)s << 6) + 4 * fq);
      ax += w * h.x; ay += w * h.y; az += w * h.z; aw += w * h.w;
    }
  }
#pragma unroll
  for (int off = 16; off <= 32; off <<= 1) {
    ax += __shfl_xor(ax, off); ay += __shfl_xor(ay, off);
    az += __shfl_xor(az, off); aw += __shfl_xor(aw, off);
  }
  float inv = 1.0f / d;
  ax *= inv; ay *= inv; az *= inv; aw *= inv;
  if (sub == 0) { float4 o{ax, ay, az, aw}; st4(XC + ((size_t)wid << 6) + 4 * fq, o); }
  float4 l1 = ld4(le1W + 4 * fq), l2 = ld4(le2W + 4 * fq), l3 = ld4(le3W + 4 * fq);
  float s1 = ax * l1.x + ay * l1.y + az * l1.z + aw * l1.w;
  float s2 = ax * l2.x + ay * l2.y + az * l2.z + aw * l2.w;
  float s3 = ax * l3.x + ay * l3.y + az * l3.z + aw * l3.w;
#pragma unroll
  for (int off = 1; off <= 8; off <<= 1) {
    s1 += __shfl_xor(s1, off); s2 += __shfl_xor(s2, off); s3 += __shfl_xor(s3, off);
  }
  if (lane == 0) { av[wid] = s1 + le1b[0]; bv[wid] = s2; c3[wid] = s3 + le3b[0]; }
}

// fitness: wave per node, lanes split edges
__global__ void fitness_k(const unsigned* __restrict__ cptr, const int* __restrict__ csrc,
                          const float* __restrict__ av, const float* __restrict__ bv,
                          const float* __restrict__ c3, float* __restrict__ fit) {
  int wid = blockIdx.x * (blockDim.x >> 6) + (threadIdx.x >> 6);
  int lane = threadIdx.x & 63;
  if (wid >= N_) return;
  unsigned p0 = cptr[wid], p1 = cptr[wid + 1];
  float s = 0.0f;
  for (unsigned p = p0 + lane; p < p1; p += 64) s += av[csrc[p]];
#pragma unroll
  for (int off = 1; off <= 32; off <<= 1) s += __shfl_xor(s, off);
  if (lane == 0) {
    float deg = (float)(p1 - p0);
    float val = s - deg * bv[wid] + c3[wid];
    fit[wid] = 1.0f / (1.0f + expf(-val));
  }
}

// ---------------------------------------------------------------------------
// Single-block exact top-K v3: fit bits staged in LDS; 4x8-bit radix select
// (fit>0 so bit order == value order); single-wave shfl scans; exact
// smallest-index tie-break; rank-sort of the 256 winners. ~25 barriers total.
// ---------------------------------------------------------------------------
__global__ __launch_bounds__(1024) void topk_k(const float* __restrict__ fit,
                                               unsigned* __restrict__ perm_i,
                                               float* __restrict__ fit_s,
                                               float* __restrict__ out_perm) {
  __shared__ unsigned fb_s[N_];          // 80000 B (gfx950: 160 KiB LDS/CU)
  __shared__ unsigned hist[256 * 16];    // 16384 B
  __shared__ unsigned scn[256];
  __shared__ unsigned long long keys[K_];
  __shared__ unsigned rnk[K_];
  __shared__ unsigned s_pfx, s_rem, s_cnt, s_bstar, s_rem2, s_cut, s_all;
  int t = threadIdx.x;
  int sub = t & 15;
  int wv = t >> 6, ln = t & 63;

  for (int i = t; i < N_; i += 1024) fb_s[i] = __float_as_uint(fit[i]);
  if (t == 0) { s_cnt = 0; s_all = 0; }
  if (t < K_) rnk[t] = 0;
  __syncthreads();

  unsigned msk = 0, pfx = 0, rem = K_;
  for (int lvl = 0; lvl < 4; ++lvl) {
    const int shift = 24 - lvl * 8;
    for (int i = t; i < 256 * 16; i += 1024) hist[i] = 0;
    __syncthreads();
    for (int i = t; i < N_; i += 1024) {
      unsigned fb = fb_s[i];
      if ((fb & msk) == pfx)
        atomicAdd(&hist[(((fb >> shift) & 0xFF) << 4) + sub], 1u);
    }
    __syncthreads();
    if (t < 256) {
      unsigned h = 0;
#pragma unroll
      for (int s = 0; s < 16; ++s) h += hist[(t << 4) + s];
      scn[t] = h;
    }
    __syncthreads();
    if (wv == 0) {  // suffix-scan 256 bins in one wave (4 bins/lane)
      unsigned b0 = scn[4 * ln], b1 = scn[4 * ln + 1], b2 = scn[4 * ln + 2], b3 = scn[4 * ln + 3];
      unsigned loc = b0 + b1 + b2 + b3;
      unsigned suf = loc;
      for (int off = 1; off < 64; off <<= 1) {
        unsigned v = __shfl_down(suf, off);
        if (ln + off < 64) suf += v;
      }
      unsigned above = suf - loc;          // sum of bins > 4ln+3
      unsigned s3 = above + b3;
      unsigned s2 = s3 + b2;
      unsigned s1 = s2 + b1;
      unsigned s0 = s1 + b0;
      if (s0 >= rem && s1 < rem)    { s_pfx = pfx | ((unsigned)(4 * ln)     << shift); s_rem = rem - s1; }
      if (s1 >= rem && s2 < rem)    { s_pfx = pfx | ((unsigned)(4 * ln + 1) << shift); s_rem = rem - s2; }
      if (s2 >= rem && s3 < rem)    { s_pfx = pfx | ((unsigned)(4 * ln + 2) << shift); s_rem = rem - s3; }
      if (s3 >= rem && above < rem) { s_pfx = pfx | ((unsigned)(4 * ln + 3) << shift); s_rem = rem - above; }
    }
    __syncthreads();
    pfx = s_pfx; rem = s_rem; msk |= (0xFFu << shift);
  }
  // pfx = exact bits of K-th largest; rem = #ties to take (smallest indices).
  for (int i = t; i < 256 * 16; i += 1024) hist[i] = 0;
  __syncthreads();
  // fused: emit strict winners + histogram ties by idx>>7 (157 bins)
  for (int i = t; i < N_; i += 1024) {
    unsigned fb = fb_s[i];
    if (fb > pfx) {
      unsigned j = atomicAdd(&s_cnt, 1u);
      keys[j] = ((unsigned long long)fb << 32) | (unsigned long long)(0xFFFFFFFFu - (unsigned)i);
    } else if (fb == pfx) {
      atomicAdd(&hist[((i >> 7) << 4) + sub], 1u);
    }
  }
  __syncthreads();
  if (t < 256) {
    unsigned h = 0;
#pragma unroll
    for (int s = 0; s < 16; ++s) h += hist[(t << 4) + s];
    scn[t] = h;
  }
  __syncthreads();
  if (wv == 0) {  // prefix-scan 256 bins in one wave
    unsigned b0 = scn[4 * ln], b1 = scn[4 * ln + 1], b2 = scn[4 * ln + 2], b3 = scn[4 * ln + 3];
    unsigned loc = b0 + b1 + b2 + b3;
    unsigned pre = loc;
    for (int off = 1; off < 64; off <<= 1) {
      unsigned v = __shfl_up(pre, off);
      if (ln >= off) pre += v;
    }
    unsigned below = pre - loc;
    unsigned p0 = below + b0;
    unsigned p1 = p0 + b1;
    unsigned p2 = p1 + b2;
    unsigned p3 = p2 + b3;
    if (ln == 63 && p3 == rem) s_all = 1u;   // all ties taken
    if (p0 >= rem && below < rem) { s_bstar = 4u * ln;     s_rem2 = rem - below; }
    if (p1 >= rem && p0 < rem)    { s_bstar = 4u * ln + 1; s_rem2 = rem - p0; }
    if (p2 >= rem && p1 < rem)    { s_bstar = 4u * ln + 2; s_rem2 = rem - p1; }
    if (p3 >= rem && p2 < rem)    { s_bstar = 4u * ln + 3; s_rem2 = rem - p2; }
  }
  __syncthreads();
  unsigned bstar = s_bstar, rem2 = s_rem2;
  if (s_all) {
    for (int i = t; i < N_; i += 1024)
      if (fb_s[i] == pfx) {
        unsigned j = atomicAdd(&s_cnt, 1u);
        keys[j] = ((unsigned long long)pfx << 32) | (unsigned long long)(0xFFFFFFFFu - (unsigned)i);
      }
  } else {
    // tie level B: bins = idx & 127 within bstar (unique -> h in {0,1})
    for (int i = t; i < 256 * 16; i += 1024) hist[i] = 0;
    __syncthreads();
    for (int i = t; i < N_; i += 1024)
      if (fb_s[i] == pfx && (unsigned)(i >> 7) == bstar)
        atomicAdd(&hist[((i & 127) << 4) + sub], 1u);
    __syncthreads();
    if (t < 128) {
      unsigned h = 0;
#pragma unroll
      for (int s = 0; s < 16; ++s) h += hist[(t << 4) + s];
      scn[t] = h;
    }
    __syncthreads();
    if (wv == 0) {  // prefix-scan 128 bins (2/lane)
      unsigned b0 = scn[2 * ln], b1 = scn[2 * ln + 1];
      unsigned loc = b0 + b1;
      unsigned pre = loc;
      for (int off = 1; off < 64; off <<= 1) {
        unsigned v = __shfl_up(pre, off);
        if (ln >= off) pre += v;
      }
      unsigned below = pre - loc;
      unsigned p0 = below + b0;
      unsigned p1 = p0 + b1;
      if (p0 >= rem2 && below < rem2) s_cut = 2u * ln;
      if (p1 >= rem2 && p0 < rem2)    s_cut = 2u * ln + 1;
    }
    __syncthreads();
    unsigned cut = s_cut;
    for (int i = t; i < N_; i += 1024) {
      if (fb_s[i] == pfx) {
        unsigned hi = (unsigned)(i >> 7), lo = (unsigned)(i & 127);
        if (hi < bstar || (hi == bstar && lo <= cut)) {
          unsigned j = atomicAdd(&s_cnt, 1u);
          keys[j] = ((unsigned long long)pfx << 32) | (unsigned long long)(0xFFFFFFFFu - (unsigned)i);
        }
      }
    }
  }
  __syncthreads();
  // rank sort: 1024 threads, key t&255, segment t>>8 (64 comparisons each)
  {
    int k = t & 255, seg = t >> 8;
    unsigned long long my = keys[k];
    unsigned r = 0;
    for (int j = seg * 64; j < seg * 64 + 64; ++j) r += (keys[j] > my) ? 1u : 0u;
    if (r) atomicAdd(&rnk[k], r);
  }
  __syncthreads();
  if (t < K_) {
    unsigned long long kk = keys[t];
    unsigned r = rnk[t];
    unsigned idx = 0xFFFFFFFFu - (unsigned)(kk & 0xFFFFFFFFu);
    perm_i[r] = idx;
    fit_s[r] = __uint_as_float((unsigned)(kk >> 32));
    out_perm[r] = (float)idx;
  }
}

__global__ void xnew_k(const float* __restrict__ XC, const unsigned* __restrict__ perm_i,
                       const float* __restrict__ fit_s, float* __restrict__ out) {
  int g = blockIdx.x * blockDim.x + threadIdx.x;
  if (g >= K_ * F_ / 4) return;
  int k = g >> 4, fq = g & 15;
  float4 v = ld4(XC + ((size_t)perm_i[k] << 6) + 4 * fq);
  float f = fit_s[k];
  v.x *= f; v.y *= f; v.z *= f; v.w *= f;
  st4(out + ((size_t)k << 6) + 4 * fq, v);
}

// build S triplets directly from the 256 selected nodes' CSR ranges
__global__ void trip_sel_k(const unsigned* __restrict__ perm_i, const unsigned* __restrict__ cptr,
                           const int* __restrict__ csrc, const float* __restrict__ sc,
                           const float* __restrict__ den,
                           int* __restrict__ ti, int* __restrict__ tk, float* __restrict__ tv,
                           unsigned* __restrict__ tcnt, unsigned* __restrict__ ctrl) {
  int k = blockIdx.x * blockDim.x + threadIdx.x;
  if (k >= K_) return;
  unsigned i = perm_i[k];
  unsigned p0 = cptr[i], p1 = cptr[i + 1];
  float d = den[i];
  for (unsigned p = p0; p < p1; ++p) {
    unsigned j = atomicAdd(&ctrl[5], 1u);
    if (j < (unsigned)TCAP) {
      int r = csrc[p];
      ti[j] = r; tk[j] = k; tv[j] = sc[p] / d;
      atomicAdd(&tcnt[r], 1u);
    }
  }
}

__global__ void trip_scatter_k(const int* __restrict__ ti, const unsigned* __restrict__ tptr,
                               unsigned* __restrict__ tcur, unsigned* __restrict__ tidx,
                               const unsigned* __restrict__ ctrl) {
  int g = blockIdx.x * blockDim.x + threadIdx.x;
  unsigned cnt = ctrl[5]; if (cnt > (unsigned)TCAP) cnt = TCAP;
  if (g >= (int)cnt) return;
  int i = ti[g];
  unsigned pos = tptr[i] + atomicAdd(&tcur[i], 1u);
  tidx[pos] = (unsigned)g;
}

// A[k1,k2] += sum over edges of S[row,k1]*S[col,k2]
__global__ void anew_k(const int* __restrict__ ei,
                       const unsigned* __restrict__ tptr, const unsigned* __restrict__ tidx,
                       const int* __restrict__ tk, const float* __restrict__ tv,
                       float* __restrict__ A) {
  int g = blockIdx.x * blockDim.x + threadIdx.x;
  if (g >= M_) return;
  int i, j;
  if (g < E_) { i = ei[g]; j = ei[E_ + g]; } else { i = j = g - E_; }
  unsigned a0 = tptr[i], a1 = tptr[i + 1];
  if (a0 == a1) return;
  unsigned b0 = tptr[j], b1 = tptr[j + 1];
  if (b0 == b1) return;
  for (unsigned pa = a0; pa < a1; ++pa) {
    unsigned ta = tidx[pa];
    int k1 = tk[ta];
    float va = tv[ta];
    float* Arow = A + (size_t)k1 * K_;
    for (unsigned pb = b0; pb < b1; ++pb) {
      unsigned tb = tidx[pb];
      atomicAdd(&Arow[tk[tb]], va * tv[tb]);
    }
  }
}

__global__ void adiag_k(float* __restrict__ A) {
  int t = threadIdx.x;
  if (t < K_) A[(size_t)t * K_ + t] = 1.0f;
}

// ---------------------------------------------------------------------------
extern "C" void kernel_launch(void* const* d_in, const int* in_sizes, int n_in,
                              void* d_out, int out_size, void* d_ws, size_t ws_size,
                              hipStream_t stream) {
  const float* x     = (const float*)d_in[0];
  const int*   ei    = (const int*)d_in[1];
  const float* W0    = (const float*)d_in[2];
  const float* b0    = (const float*)d_in[3];
  const float* W1    = (const float*)d_in[4];
  const float* b1    = (const float*)d_in[5];
  const float* linW  = (const float*)d_in[6];
  const float* linb  = (const float*)d_in[7];
  const float* attW  = (const float*)d_in[8];
  const float* attb  = (const float*)d_in[9];
  const float* le1W  = (const float*)d_in[10];
  const float* le1b  = (const float*)d_in[11];
  const float* le2W  = (const float*)d_in[12];
  const float* le3W  = (const float*)d_in[13];
  const float* le3b  = (const float*)d_in[14];

  float*    wf = (float*)d_ws;
  unsigned* wu = (unsigned*)d_ws;
  int*      wi = (int*)d_ws;
  float*    out = (float*)d_out;

  int*      csrc  = wi + O_CSRC;
  float*    cnrm  = wf + O_CNRM;
  float*    sc    = wf + O_SC;
  float*    bufA  = wf + O_BUFA;
  float*    bufB  = wf + O_BUFB;
  float*    bufC  = wf + O_BUFC;
  unsigned* cptr  = wu + O_CPTR;
  float*    q2    = wf + O_Q2;
  float*    den   = wf + O_DEN;
  float*    av    = wf + O_AV;
  float*    bv    = wf + O_BV;
  float*    c3    = wf + O_C3;
  float*    fit   = wf + O_FIT;
  unsigned* tptr  = wu + O_TPTR;
  int*      ti    = wi + O_TI;
  int*      tk    = wi + O_TK;
  float*    tv    = wf + O_TV;
  unsigned* tidx  = wu + O_TIDX;
  unsigned* perm_i= wu + O_PERM;
  float*    fit_s = wf + O_FITS;
  float*    wq    = wf + O_WQ;
  unsigned* zr    = wu + O_ZR;
  unsigned* cnt   = wu + O_CNT;
  unsigned* cur   = wu + O_CUR;
  unsigned* tcnt  = wu + O_TCNT;
  unsigned* tcur  = wu + O_TCUR;
  unsigned* ctrl  = wu + O_CTRL;

  const int TB = 256;
  const int gM = (M_ + TB - 1) / TB;          // 1329
  const int gW = (N_ + 3) / 4;                // 5000 (wave-per-node, 4 waves/block)
  const int gG = (N_ + 63) / 64;              // 313 (gemm tiles)
  const int gZ = ((int)(ZR_WORDS > OUT_WORDS ? ZR_WORDS : OUT_WORDS) + TB - 1) / TB;

  hipLaunchKernelGGL(init_k, dim3(gZ), dim3(TB), 0, stream, zr, out);
  hipLaunchKernelGGL(build_edges_k, dim3(gM + 1), dim3(TB), 0, stream, ei, cnt,
                     linW, linb, attW, wq);
  hipLaunchKernelGGL(prefix_k, dim3(1), dim3(1024), 0, stream, cnt, cptr, N_);
  hipLaunchKernelGGL(scatter_csr_k, dim3(gM), dim3(TB), 0, stream, ei, cptr, cur, csrc, cnrm);

  // GCN layer 1: bufA = x@W0 ; bufB = relu(agg + b0)
  hipLaunchKernelGGL(gemm64_k, dim3(gG), dim3(TB), 0, stream, x, W0, bufA);
  hipLaunchKernelGGL((agg_gcn_k<0>), dim3(gW), dim3(TB), 0, stream, bufA, csrc, cnrm, cptr, b0, bufB,
                     nullptr, nullptr);
  // GCN layer 2: bufA = bufB@W1 ; bufC = relu(agg + b1) = x2 ; q2 epilogue
  hipLaunchKernelGGL(gemm64_k, dim3(gG), dim3(TB), 0, stream, bufB, W1, bufA);
  hipLaunchKernelGGL((agg_gcn_k<1>), dim3(gW), dim3(TB), 0, stream, bufA, csrc, cnrm, cptr, b1, bufC,
                     attW, q2);

  // fused attention pooling (xc -> bufB) + le dots
  hipLaunchKernelGGL(attn_fused_k, dim3(gW), dim3(TB), 0, stream, bufC, csrc, cptr, q2, attb, wq,
                     sc, den, bufB, le1W, le1b, le2W, le3W, le3b, av, bv, c3);

  // fitness + exact top-K
  hipLaunchKernelGGL(fitness_k, dim3(gW), dim3(TB), 0, stream, cptr, csrc, av, bv, c3, fit);
  hipLaunchKernelGGL(topk_k, dim3(1), dim3(1024), 0, stream, fit, perm_i, fit_s, out + K_ * F_ + K_ * K_);
  hipLaunchKernelGGL(xnew_k, dim3((K_ * F_ / 4 + TB - 1) / TB), dim3(TB), 0, stream, bufB, perm_i, fit_s, out);

  // sparse S triplets -> A_new
  hipLaunchKernelGGL(trip_sel_k, dim3(1), dim3(TB), 0, stream, perm_i, cptr, csrc, sc, den, ti, tk, tv, tcnt, ctrl);
  hipLaunchKernelGGL(prefix_k, dim3(1), dim3(1024), 0, stream, tcnt, tptr, N_);
  hipLaunchKernelGGL(trip_scatter_k, dim3(TCAP / TB), dim3(TB), 0, stream, ti, tptr, tcur, tidx, ctrl);
  hipLaunchKernelGGL(anew_k, dim3(gM), dim3(TB), 0, stream, ei, tptr, tidx, tk, tv, out + K_ * F_);
  hipLaunchKernelGGL(adiag_k, dim3(1), dim3(TB), 0, stream, out + K_ * F_);

  (void)in_sizes; (void)n_in; (void)out_size; (void)ws_size;
}